// Round 1
// baseline (1413.502 us; speedup 1.0000x reference)
//
#include <hip/hip_runtime.h>
#include <math.h>

constexpr int kN = 8192;
constexpr int kE = 131072;

__device__ __forceinline__ float silu_f(float x) { return x / (1.f + __expf(-x)); }

__global__ __launch_bounds__(256) void zero_ints_kernel(int* __restrict__ a, int* __restrict__ b) {
  int i = blockIdx.x * 256 + threadIdx.x;
  if (i < kN) { a[i] = 0; b[i] = 0; }
}

__global__ __launch_bounds__(256) void elem_kernel(const float* __restrict__ attrs, int* __restrict__ elem) {
  int n = blockIdx.x * 256 + threadIdx.x;
  if (n >= kN) return;
  const float* a = attrs + (size_t)n * 10;
  int best = 0; float bv = a[0];
  #pragma unroll
  for (int z = 1; z < 10; ++z) { float v = a[z]; if (v > bv) { bv = v; best = z; } }
  elem[n] = best;
}

__global__ __launch_bounds__(256) void init_feats_kernel(const float* __restrict__ W_embed,
                                                         const int* __restrict__ elem,
                                                         float* __restrict__ F) {
  int i = blockIdx.x * 256 + threadIdx.x;   // n*128 + c
  int n = i >> 7, c = i & 127;
  F[(size_t)n * 2048 + c] = W_embed[(size_t)elem[n] * 128 + c];
}

__global__ __launch_bounds__(256) void geom_kernel(const float* __restrict__ pos,
                                                   const float* __restrict__ shifts,
                                                   const int* __restrict__ ei,
                                                   float* __restrict__ sh,
                                                   float* __restrict__ rb) {
  int e = blockIdx.x * 256 + threadIdx.x;
  if (e >= kE) return;
  int s = ei[e], r = ei[kE + e];
  float vx = pos[r*3+0] - pos[s*3+0] + shifts[(size_t)e*3+0];
  float vy = pos[r*3+1] - pos[s*3+1] + shifts[(size_t)e*3+1];
  float vz = pos[r*3+2] - pos[s*3+2] + shifts[(size_t)e*3+2];
  float len = sqrtf(vx*vx + vy*vy + vz*vz) + 1e-9f;
  float inv = 1.f / len;
  float x = vx*inv, y = vy*inv, z = vz*inv;
  float x2 = x*x, y2 = y*y, z2 = z*z;
  const float s3  = 1.7320508075688772f;
  const float s5  = 2.2360679774997896f;
  const float s15 = 3.8729833462074170f;
  const float a33 = 2.0916500663351889f;   // 0.25*sqrt(70)
  const float a32 = 10.246950765959598f;   // sqrt(105)
  const float a31 = 1.6201851746019651f;   // 0.25*sqrt(42)
  const float a30 = 1.3228756555322954f;   // 0.5*sqrt(7)
  float4* shp = (float4*)(sh + (size_t)e * 16);
  shp[0] = make_float4(1.f, s3*x, s3*y, s3*z);
  shp[1] = make_float4(s15*x*y, s15*y*z, 0.5f*s5*(3.f*z2 - 1.f), s15*x*z);
  shp[2] = make_float4(0.5f*s15*(x2 - y2), a33*y*(3.f*x2 - y2), a32*x*y*z, a31*y*(5.f*z2 - 1.f));
  shp[3] = make_float4(a30*z*(5.f*z2 - 3.f), a31*x*(5.f*z2 - 1.f), 0.5f*a32*z*(x2 - y2), a33*x*(x2 - 3.f*y2));
  float xr = len * 0.2f;            // r / R_MAX
  float cut = 0.f;
  if (xr < 1.f) {
    float x5 = xr*xr*xr*xr*xr;
    cut = 1.f - 21.f*x5 + 35.f*x5*xr - 15.f*x5*xr*xr;
  }
  float pref = 0.63245553203367587f * cut * inv;   // sqrt(2/5)*cut/r
  const float PI = 3.14159265358979323846f;
  float b[8];
  #pragma unroll
  for (int k = 0; k < 8; ++k) b[k] = pref * sinf((float)(k+1) * PI * xr);
  float4* rbp = (float4*)(rb + (size_t)e * 8);
  rbp[0] = make_float4(b[0], b[1], b[2], b[3]);
  rbp[1] = make_float4(b[4], b[5], b[6], b[7]);
}

__global__ __launch_bounds__(256) void count_kernel(const int* __restrict__ ei, int* __restrict__ counts) {
  int e = blockIdx.x * 256 + threadIdx.x;
  if (e < kE) atomicAdd(&counts[ei[kE + e]], 1);
}

__global__ __launch_bounds__(1024) void scan_kernel(const int* __restrict__ counts, int* __restrict__ offs) {
  __shared__ int tmp[1024];
  int t = threadIdx.x;
  int loc[8]; int s = 0;
  #pragma unroll
  for (int i = 0; i < 8; ++i) { loc[i] = s; s += counts[t*8 + i]; }
  tmp[t] = s;
  __syncthreads();
  for (int d = 1; d < 1024; d <<= 1) {
    int v = (t >= d) ? tmp[t - d] : 0;
    __syncthreads();
    tmp[t] += v;
    __syncthreads();
  }
  int pre = (t == 0) ? 0 : tmp[t - 1];
  #pragma unroll
  for (int i = 0; i < 8; ++i) offs[t*8 + i] = pre + loc[i];
  if (t == 1023) offs[kN] = tmp[1023];
}

__global__ __launch_bounds__(256) void fill_kernel(const int* __restrict__ ei, const int* __restrict__ offs,
                                                   int* __restrict__ cursor, int* __restrict__ eids) {
  int e = blockIdx.x * 256 + threadIdx.x;
  if (e >= kE) return;
  int r = ei[kE + e];
  int pos = atomicAdd(&cursor[r], 1);
  eids[offs[r] + pos] = e;
}

__global__ __launch_bounds__(256) void radial_kernel(const float* __restrict__ rb,
                                                     const float* __restrict__ W1,
                                                     const float* __restrict__ W2,
                                                     float* __restrict__ r2) {
  __shared__ float W1s[8*64];
  __shared__ float W2s[64*64];
  __shared__ float r1s[4][64];
  int tid = threadIdx.x;
  for (int i = tid; i < 512; i += 256) W1s[i] = W1[i];
  for (int i = tid; i < 4096; i += 256) W2s[i] = W2[i];
  __syncthreads();
  int g = tid >> 6, j = tid & 63;
  int e = blockIdx.x * 4 + g;
  const float* rbe = rb + (size_t)e * 8;
  float v = 0.f;
  #pragma unroll
  for (int i = 0; i < 8; ++i) v = fmaf(rbe[i], W1s[i*64 + j], v);
  r1s[g][j] = silu_f(v);
  __syncthreads();
  float u = 0.f;
  #pragma unroll
  for (int i = 0; i < 64; ++i) u = fmaf(r1s[g][i], W2s[i*64 + j], u);
  r2[(size_t)e * 64 + j] = silu_f(u);
}

__global__ __launch_bounds__(256) void permute_r3_kernel(const float* __restrict__ R3L, float* __restrict__ R3P) {
  int i = blockIdx.x * 256 + threadIdx.x;   // t*64 + j, t = l*128 + c
  int j = i & 63, t = i >> 6;
  int l = t >> 7, c = t & 127;
  R3P[i] = R3L[j * 512 + (c << 2) + l];
}

// Out[row, d] = sum_c A[row*aStride + c] * W[c*128 + d]   (K = 128, Ncols = 128)
// SCALED: A element (row, c) multiplied by scaleBuf[(row>>4)*128 + c]
// EPI: Out += H[row*128 + d] * wscL[elem[row>>4]*128 + d]  (only rows with row%16==0 if l0flag)
template<bool SCALED, bool EPI>
__global__ __launch_bounds__(256) void gemm128_kernel(
    const float* __restrict__ A, int aStride,
    const float* __restrict__ W,
    float* __restrict__ O, int oStride,
    const float* __restrict__ scaleBuf,
    const float* __restrict__ Hbuf,
    const float* __restrict__ wscL,
    const int* __restrict__ elem,
    int l0flag)
{
  __shared__ float As[128*132];   // k-major, +4 pad
  __shared__ float Bs[128*128];
  const int tid = threadIdx.x;
  const size_t rowbase = (size_t)blockIdx.x * 128;
  {
    int k0 = tid >> 5, c4 = (tid & 31) * 4;
    #pragma unroll
    for (int it = 0; it < 16; ++it) {
      int kk = k0 + it*8;
      *(float4*)&Bs[kk*128 + c4] = *(const float4*)&W[kk*128 + c4];
    }
  }
  {
    int kk = tid & 31, rr = tid >> 5;
    #pragma unroll
    for (int it = 0; it < 16; ++it) {
      int r = rr + it*8;
      size_t grow = rowbase + r;
      const float* ap = A + grow * (size_t)aStride;
      #pragma unroll
      for (int q = 0; q < 4; ++q) {
        int k = kk + 32*q;
        float v = ap[k];
        if (SCALED) v *= scaleBuf[(grow >> 4) * 128 + k];
        As[k*132 + r] = v;
      }
    }
  }
  __syncthreads();
  const int tr = (tid >> 4) * 8, tc = (tid & 15) * 8;
  float acc[8][8] = {};
  #pragma unroll 2
  for (int k = 0; k < 128; ++k) {
    float4 A0 = *(const float4*)&As[k*132 + tr];
    float4 A1 = *(const float4*)&As[k*132 + tr + 4];
    float4 B0 = *(const float4*)&Bs[k*128 + tc];
    float4 B1 = *(const float4*)&Bs[k*128 + tc + 4];
    float av[8] = {A0.x,A0.y,A0.z,A0.w,A1.x,A1.y,A1.z,A1.w};
    float bv[8] = {B0.x,B0.y,B0.z,B0.w,B1.x,B1.y,B1.z,B1.w};
    #pragma unroll
    for (int i = 0; i < 8; ++i) {
      #pragma unroll
      for (int jj = 0; jj < 8; ++jj)
        acc[i][jj] = fmaf(av[i], bv[jj], acc[i][jj]);
    }
  }
  #pragma unroll
  for (int i = 0; i < 8; ++i) {
    size_t grow = rowbase + tr + i;
    if (EPI) {
      if (!l0flag || ((grow & 15) == 0)) {
        int ee = elem[grow >> 4];
        const float* hp = Hbuf + grow * 128 + tc;
        const float* wp = wscL + (size_t)ee * 128 + tc;
        #pragma unroll
        for (int jj = 0; jj < 8; ++jj) acc[i][jj] = fmaf(hp[jj], wp[jj], acc[i][jj]);
      }
    }
    *(float4*)&O[grow * (size_t)oStride + tc]     = make_float4(acc[i][0], acc[i][1], acc[i][2], acc[i][3]);
    *(float4*)&O[grow * (size_t)oStride + tc + 4] = make_float4(acc[i][4], acc[i][5], acc[i][6], acc[i][7]);
  }
}

// One block per node: AGG[n][m][c] = (1/16) * sum_{e->n} h0[send_e, c] * (r2[e]·R3[:, c*4+l(m)]) * sh[e, m]
__global__ __launch_bounds__(512) void gather_kernel(
    const int* __restrict__ offs, const int* __restrict__ eids,
    const int* __restrict__ ei,
    const float* __restrict__ r2, const float* __restrict__ sh,
    const float* __restrict__ R3P, const float* __restrict__ H,
    float* __restrict__ AGG)
{
  __shared__ float r2s[64];
  __shared__ float shs[16];
  __shared__ float h0s[128];
  int n = blockIdx.x;
  int t = threadIdx.x;
  int l = t >> 7;       // wave-uniform
  int c = t & 127;
  float r3c[64];
  {
    const float4* rp = (const float4*)(R3P + (size_t)t * 64);
    #pragma unroll
    for (int j4 = 0; j4 < 16; ++j4) {
      float4 v = rp[j4];
      r3c[j4*4+0] = v.x; r3c[j4*4+1] = v.y; r3c[j4*4+2] = v.z; r3c[j4*4+3] = v.w;
    }
  }
  float a0=0,a1=0,a2=0,a3=0,a4=0,a5=0,a6=0;
  int e0 = offs[n], e1 = offs[n+1];
  for (int ii = e0; ii < e1; ++ii) {
    int e = eids[ii];
    if (t < 64) r2s[t] = r2[(size_t)e*64 + t];
    else if (t < 80) shs[t-64] = sh[(size_t)e*16 + (t-64)];
    else if (t >= 128 && t < 256) {
      int s = ei[e];
      h0s[t-128] = H[(size_t)s*2048 + (t-128)];
    }
    __syncthreads();
    float w = 0.f;
    const float4* r2s4 = (const float4*)r2s;
    #pragma unroll
    for (int j4 = 0; j4 < 16; ++j4) {
      float4 rr = r2s4[j4];
      w = fmaf(rr.x, r3c[j4*4+0], w);
      w = fmaf(rr.y, r3c[j4*4+1], w);
      w = fmaf(rr.z, r3c[j4*4+2], w);
      w = fmaf(rr.w, r3c[j4*4+3], w);
    }
    float wh = w * h0s[c];
    if (l == 0) {
      a0 = fmaf(wh, shs[0], a0);
    } else if (l == 1) {
      a0 = fmaf(wh, shs[1], a0); a1 = fmaf(wh, shs[2], a1); a2 = fmaf(wh, shs[3], a2);
    } else if (l == 2) {
      a0 = fmaf(wh, shs[4], a0); a1 = fmaf(wh, shs[5], a1); a2 = fmaf(wh, shs[6], a2);
      a3 = fmaf(wh, shs[7], a3); a4 = fmaf(wh, shs[8], a4);
    } else {
      a0 = fmaf(wh, shs[9], a0);  a1 = fmaf(wh, shs[10], a1); a2 = fmaf(wh, shs[11], a2);
      a3 = fmaf(wh, shs[12], a3); a4 = fmaf(wh, shs[13], a4); a5 = fmaf(wh, shs[14], a5);
      a6 = fmaf(wh, shs[15], a6);
    }
    __syncthreads();
  }
  const float inv16 = 0.0625f;
  size_t base = (size_t)n * 2048 + c;
  if (l == 0) {
    AGG[base] = a0 * inv16;
  } else if (l == 1) {
    AGG[base + 1*128] = a0*inv16; AGG[base + 2*128] = a1*inv16; AGG[base + 3*128] = a2*inv16;
  } else if (l == 2) {
    AGG[base + 4*128] = a0*inv16; AGG[base + 5*128] = a1*inv16; AGG[base + 6*128] = a2*inv16;
    AGG[base + 7*128] = a3*inv16; AGG[base + 8*128] = a4*inv16;
  } else {
    AGG[base + 9*128]  = a0*inv16; AGG[base + 10*128] = a1*inv16; AGG[base + 11*128] = a2*inv16;
    AGG[base + 12*128] = a3*inv16; AGG[base + 13*128] = a4*inv16; AGG[base + 14*128] = a5*inv16;
    AGG[base + 15*128] = a6*inv16;
  }
}

__global__ __launch_bounds__(256) void scale_kernel(const float* __restrict__ M,
                                                    const int* __restrict__ elem,
                                                    const float* __restrict__ wprodL,
                                                    float* __restrict__ scale) {
  int i = blockIdx.x * 256 + threadIdx.x;  // n*128 + c
  int n = i >> 7, c = i & 127;
  float s = M[(size_t)n * 2048 + c];
  const float* co = wprodL + ((size_t)elem[n] * 128 + c) * 3;
  scale[i] = co[0] + s * (co[1] + s * co[2]);
}

__global__ __launch_bounds__(64) void readout_kernel(const float* __restrict__ F,
                                                     const float* __restrict__ ro0,
                                                     const float* __restrict__ ro1,
                                                     const float* __restrict__ ro2,
                                                     float* __restrict__ out, int layer) {
  int n = blockIdx.x; int t = threadIdx.x;
  const float* fr = F + (size_t)n * 2048;   // feats[n][0][:]
  float f0 = fr[t], f1 = fr[t + 64];
  if (layer == 0) {
    float v = f0 * ro0[t] + f1 * ro0[t + 64];
    #pragma unroll
    for (int m = 32; m > 0; m >>= 1) v += __shfl_xor(v, m, 64);
    if (t == 0) out[n] = v;
  } else {
    float acc = 0.f;
    for (int h = 0; h < 16; ++h) {
      float p = f0 * ro1[t*16 + h] + f1 * ro1[(t + 64)*16 + h];
      #pragma unroll
      for (int m = 32; m > 0; m >>= 1) p += __shfl_xor(p, m, 64);
      acc = fmaf(silu_f(p), ro2[h], acc);
    }
    if (t == 0) out[n] += acc;
  }
}

extern "C" void kernel_launch(void* const* d_in, const int* in_sizes, int n_in,
                              void* d_out, int out_size, void* d_ws, size_t ws_size,
                              hipStream_t stream) {
  (void)in_sizes; (void)n_in; (void)out_size;
  const float* positions = (const float*)d_in[0];
  const float* node_attrs= (const float*)d_in[1];
  const float* shifts    = (const float*)d_in[2];
  const float* W_embed   = (const float*)d_in[3];
  const float* W_up      = (const float*)d_in[4];
  const float* R_w1      = (const float*)d_in[5];
  const float* R_w2      = (const float*)d_in[6];
  const float* R_w3      = (const float*)d_in[7];
  const float* W_out     = (const float*)d_in[8];
  const float* w_sc      = (const float*)d_in[9];
  const float* w_prod    = (const float*)d_in[10];
  const float* W_plin    = (const float*)d_in[11];
  const float* w_ro0     = (const float*)d_in[12];
  const float* ro_w1     = (const float*)d_in[13];
  const float* ro_w2     = (const float*)d_in[14];
  const int*   ei        = (const int*)d_in[15];
  float* out = (float*)d_out;

  char* ws = (char*)d_ws;
  size_t off = 0;
  auto alloc = [&](size_t nbytes) -> void* {
    void* p = ws + off;
    off += (nbytes + 255) & ~(size_t)255;
    return p;
  };
  const size_t PB = (size_t)kN * 16 * 128 * sizeof(float);  // 67 MB
  float* P0     = (float*)alloc(PB);
  float* P1     = (float*)alloc(PB);
  float* P2     = (float*)alloc(PB);
  float* shb    = (float*)alloc((size_t)kE * 16 * 4);
  float* rbb    = (float*)alloc((size_t)kE * 8 * 4);
  float* r2b    = (float*)alloc((size_t)kE * 64 * 4);
  float* scaleb = (float*)alloc((size_t)kN * 128 * 4);
  float* R3P    = (float*)alloc(64 * 512 * 4);
  int* elemb  = (int*)alloc(kN * 4);
  int* counts = (int*)alloc(kN * 4);
  int* cursor = (int*)alloc(kN * 4);
  int* offsb  = (int*)alloc((kN + 1) * 4);
  int* eidsb  = (int*)alloc((size_t)kE * 4);
  if (off > ws_size) return;  // workspace too small: bail (will fail validation loudly)

  // ---- prep ----
  zero_ints_kernel<<<kN/256, 256, 0, stream>>>(counts, cursor);
  elem_kernel<<<kN/256, 256, 0, stream>>>(node_attrs, elemb);
  init_feats_kernel<<<(kN*128)/256, 256, 0, stream>>>(W_embed, elemb, P0);
  geom_kernel<<<kE/256, 256, 0, stream>>>(positions, shifts, ei, shb, rbb);
  count_kernel<<<kE/256, 256, 0, stream>>>(ei, counts);
  scan_kernel<<<1, 1024, 0, stream>>>(counts, offsb);
  fill_kernel<<<kE/256, 256, 0, stream>>>(ei, offsb, cursor, eidsb);

  // ---- layer 0 (feats nonzero only at m=0 -> strided h-einsum over 8192 rows) ----
  radial_kernel<<<kE/4, 256, 0, stream>>>(rbb, R_w1, R_w2, r2b);
  gemm128_kernel<false,false><<<kN/128, 256, 0, stream>>>(P0, 2048, W_up, P1, 2048,
                                                          nullptr, nullptr, nullptr, nullptr, 0);
  permute_r3_kernel<<<(64*512)/256, 256, 0, stream>>>(R_w3, R3P);
  gather_kernel<<<kN, 512, 0, stream>>>(offsb, eidsb, ei, r2b, shb, R3P, P1, P2);
  gemm128_kernel<false,false><<<(kN*16)/128, 256, 0, stream>>>(P2, 128, W_out, P0, 128,
                                                               nullptr, nullptr, nullptr, nullptr, 0);
  scale_kernel<<<(kN*128)/256, 256, 0, stream>>>(P0, elemb, w_prod, scaleb);
  gemm128_kernel<true,true><<<(kN*16)/128, 256, 0, stream>>>(P0, 128, W_plin, P2, 128,
                                                             scaleb, P1, w_sc, elemb, 1);
  readout_kernel<<<kN, 64, 0, stream>>>(P2, w_ro0, ro_w1, ro_w2, out, 0);

  // ---- layer 1 ----
  radial_kernel<<<kE/4, 256, 0, stream>>>(rbb, R_w1 + 512, R_w2 + 4096, r2b);
  gemm128_kernel<false,false><<<(kN*16)/128, 256, 0, stream>>>(P2, 128, W_up + 16384, P1, 128,
                                                               nullptr, nullptr, nullptr, nullptr, 0);
  permute_r3_kernel<<<(64*512)/256, 256, 0, stream>>>(R_w3 + 32768, R3P);
  gather_kernel<<<kN, 512, 0, stream>>>(offsb, eidsb, ei, r2b, shb, R3P, P1, P0);
  gemm128_kernel<false,false><<<(kN*16)/128, 256, 0, stream>>>(P0, 128, W_out + 16384, P2, 128,
                                                               nullptr, nullptr, nullptr, nullptr, 0);
  scale_kernel<<<(kN*128)/256, 256, 0, stream>>>(P2, elemb, w_prod + 3840, scaleb);
  gemm128_kernel<true,true><<<(kN*16)/128, 256, 0, stream>>>(P2, 128, W_plin + 16384, P0, 128,
                                                             scaleb, P1, w_sc + 1280, elemb, 0);
  readout_kernel<<<kN, 64, 0, stream>>>(P0, w_ro0, ro_w1, ro_w2, out, 1);
}

// Round 2
// 1300.252 us; speedup vs baseline: 1.0871x; 1.0871x over previous
//
#include <hip/hip_runtime.h>
#include <math.h>

constexpr int kN = 8192;
constexpr int kE = 131072;

__device__ __forceinline__ float silu_f(float x) { return x / (1.f + __expf(-x)); }

__global__ __launch_bounds__(256) void zero_ints_kernel(int* __restrict__ a, int* __restrict__ b) {
  int i = blockIdx.x * 256 + threadIdx.x;
  if (i < kN) { a[i] = 0; b[i] = 0; }
}

__global__ __launch_bounds__(256) void elem_kernel(const float* __restrict__ attrs, int* __restrict__ elem) {
  int n = blockIdx.x * 256 + threadIdx.x;
  if (n >= kN) return;
  const float* a = attrs + (size_t)n * 10;
  int best = 0; float bv = a[0];
  #pragma unroll
  for (int z = 1; z < 10; ++z) { float v = a[z]; if (v > bv) { bv = v; best = z; } }
  elem[n] = best;
}

__global__ __launch_bounds__(256) void init_feats_kernel(const float* __restrict__ W_embed,
                                                         const int* __restrict__ elem,
                                                         float* __restrict__ F) {
  int i = blockIdx.x * 256 + threadIdx.x;   // n*128 + c
  int n = i >> 7, c = i & 127;
  F[(size_t)n * 2048 + c] = W_embed[(size_t)elem[n] * 128 + c];
}

__global__ __launch_bounds__(256) void geom_kernel(const float* __restrict__ pos,
                                                   const float* __restrict__ shifts,
                                                   const int* __restrict__ ei,
                                                   float* __restrict__ sh,
                                                   float* __restrict__ rb) {
  int e = blockIdx.x * 256 + threadIdx.x;
  if (e >= kE) return;
  int s = ei[e], r = ei[kE + e];
  float vx = pos[r*3+0] - pos[s*3+0] + shifts[(size_t)e*3+0];
  float vy = pos[r*3+1] - pos[s*3+1] + shifts[(size_t)e*3+1];
  float vz = pos[r*3+2] - pos[s*3+2] + shifts[(size_t)e*3+2];
  float len = sqrtf(vx*vx + vy*vy + vz*vz) + 1e-9f;
  float inv = 1.f / len;
  float x = vx*inv, y = vy*inv, z = vz*inv;
  float x2 = x*x, y2 = y*y, z2 = z*z;
  const float s3  = 1.7320508075688772f;
  const float s5  = 2.2360679774997896f;
  const float s15 = 3.8729833462074170f;
  const float a33 = 2.0916500663351889f;   // 0.25*sqrt(70)
  const float a32 = 10.246950765959598f;   // sqrt(105)
  const float a31 = 1.6201851746019651f;   // 0.25*sqrt(42)
  const float a30 = 1.3228756555322954f;   // 0.5*sqrt(7)
  float4* shp = (float4*)(sh + (size_t)e * 16);
  shp[0] = make_float4(1.f, s3*x, s3*y, s3*z);
  shp[1] = make_float4(s15*x*y, s15*y*z, 0.5f*s5*(3.f*z2 - 1.f), s15*x*z);
  shp[2] = make_float4(0.5f*s15*(x2 - y2), a33*y*(3.f*x2 - y2), a32*x*y*z, a31*y*(5.f*z2 - 1.f));
  shp[3] = make_float4(a30*z*(5.f*z2 - 3.f), a31*x*(5.f*z2 - 1.f), 0.5f*a32*z*(x2 - y2), a33*x*(x2 - 3.f*y2));
  float xr = len * 0.2f;            // r / R_MAX
  float cut = 0.f;
  if (xr < 1.f) {
    float x5 = xr*xr*xr*xr*xr;
    cut = 1.f - 21.f*x5 + 35.f*x5*xr - 15.f*x5*xr*xr;
  }
  float pref = 0.63245553203367587f * cut * inv;   // sqrt(2/5)*cut/r
  const float PI = 3.14159265358979323846f;
  float b[8];
  #pragma unroll
  for (int k = 0; k < 8; ++k) b[k] = pref * sinf((float)(k+1) * PI * xr);
  float4* rbp = (float4*)(rb + (size_t)e * 8);
  rbp[0] = make_float4(b[0], b[1], b[2], b[3]);
  rbp[1] = make_float4(b[4], b[5], b[6], b[7]);
}

__global__ __launch_bounds__(256) void count_kernel(const int* __restrict__ ei, int* __restrict__ counts) {
  int e = blockIdx.x * 256 + threadIdx.x;
  if (e < kE) atomicAdd(&counts[ei[kE + e]], 1);
}

__global__ __launch_bounds__(1024) void scan_kernel(const int* __restrict__ counts, int* __restrict__ offs) {
  __shared__ int tmp[1024];
  int t = threadIdx.x;
  int loc[8]; int s = 0;
  #pragma unroll
  for (int i = 0; i < 8; ++i) { loc[i] = s; s += counts[t*8 + i]; }
  tmp[t] = s;
  __syncthreads();
  for (int d = 1; d < 1024; d <<= 1) {
    int v = (t >= d) ? tmp[t - d] : 0;
    __syncthreads();
    tmp[t] += v;
    __syncthreads();
  }
  int pre = (t == 0) ? 0 : tmp[t - 1];
  #pragma unroll
  for (int i = 0; i < 8; ++i) offs[t*8 + i] = pre + loc[i];
  if (t == 1023) offs[kN] = tmp[1023];
}

__global__ __launch_bounds__(256) void fill_kernel(const int* __restrict__ ei, const int* __restrict__ offs,
                                                   int* __restrict__ cursor, int* __restrict__ eids) {
  int e = blockIdx.x * 256 + threadIdx.x;
  if (e >= kE) return;
  int r = ei[kE + e];
  int pos = atomicAdd(&cursor[r], 1);
  eids[offs[r] + pos] = e;
}

__global__ __launch_bounds__(256) void radial_kernel(const float* __restrict__ rb,
                                                     const float* __restrict__ W1,
                                                     const float* __restrict__ W2,
                                                     float* __restrict__ r2) {
  __shared__ float W1s[8*64];
  __shared__ float W2s[64*64];
  __shared__ float r1s[4][64];
  int tid = threadIdx.x;
  for (int i = tid; i < 512; i += 256) W1s[i] = W1[i];
  for (int i = tid; i < 4096; i += 256) W2s[i] = W2[i];
  __syncthreads();
  int g = tid >> 6, j = tid & 63;
  int e = blockIdx.x * 4 + g;
  const float* rbe = rb + (size_t)e * 8;
  float v = 0.f;
  #pragma unroll
  for (int i = 0; i < 8; ++i) v = fmaf(rbe[i], W1s[i*64 + j], v);
  r1s[g][j] = silu_f(v);
  __syncthreads();
  float u = 0.f;
  #pragma unroll
  for (int i = 0; i < 64; ++i) u = fmaf(r1s[g][i], W2s[i*64 + j], u);
  r2[(size_t)e * 64 + j] = silu_f(u);
}

__global__ __launch_bounds__(256) void permute_r3_kernel(const float* __restrict__ R3L, float* __restrict__ R3P) {
  int i = blockIdx.x * 256 + threadIdx.x;   // t*64 + j, t = l*128 + c
  int j = i & 63, t = i >> 6;
  int l = t >> 7, c = t & 127;
  R3P[i] = R3L[j * 512 + (c << 2) + l];
}

// Out[row, d] = sum_c A[row*aStride + c] * W[c*128 + d]   (K = 128, Ncols = 128)
// SCALED: A element (row, c) multiplied by scaleBuf[(row>>4)*128 + c]
// EPI: Out += H[row*128 + d] * wscL[elem[row>>4]*128 + d]  (only rows with row%16==0 if l0flag)
template<bool SCALED, bool EPI>
__global__ __launch_bounds__(256) void gemm128_kernel(
    const float* __restrict__ A, int aStride,
    const float* __restrict__ W,
    float* __restrict__ O, int oStride,
    const float* __restrict__ scaleBuf,
    const float* __restrict__ Hbuf,
    const float* __restrict__ wscL,
    const int* __restrict__ elem,
    int l0flag)
{
  __shared__ float As[128*132];   // k-major, +4 pad
  __shared__ float Bs[128*128];
  const int tid = threadIdx.x;
  const size_t rowbase = (size_t)blockIdx.x * 128;
  {
    int k0 = tid >> 5, c4 = (tid & 31) * 4;
    #pragma unroll
    for (int it = 0; it < 16; ++it) {
      int kk = k0 + it*8;
      *(float4*)&Bs[kk*128 + c4] = *(const float4*)&W[kk*128 + c4];
    }
  }
  {
    int kk = tid & 31, rr = tid >> 5;
    #pragma unroll
    for (int it = 0; it < 16; ++it) {
      int r = rr + it*8;
      size_t grow = rowbase + r;
      const float* ap = A + grow * (size_t)aStride;
      #pragma unroll
      for (int q = 0; q < 4; ++q) {
        int k = kk + 32*q;
        float v = ap[k];
        if (SCALED) v *= scaleBuf[(grow >> 4) * 128 + k];
        As[k*132 + r] = v;
      }
    }
  }
  __syncthreads();
  const int tr = (tid >> 4) * 8, tc = (tid & 15) * 8;
  float acc[8][8] = {};
  #pragma unroll 2
  for (int k = 0; k < 128; ++k) {
    float4 A0 = *(const float4*)&As[k*132 + tr];
    float4 A1 = *(const float4*)&As[k*132 + tr + 4];
    float4 B0 = *(const float4*)&Bs[k*128 + tc];
    float4 B1 = *(const float4*)&Bs[k*128 + tc + 4];
    float av[8] = {A0.x,A0.y,A0.z,A0.w,A1.x,A1.y,A1.z,A1.w};
    float bv[8] = {B0.x,B0.y,B0.z,B0.w,B1.x,B1.y,B1.z,B1.w};
    #pragma unroll
    for (int i = 0; i < 8; ++i) {
      #pragma unroll
      for (int jj = 0; jj < 8; ++jj)
        acc[i][jj] = fmaf(av[i], bv[jj], acc[i][jj]);
    }
  }
  #pragma unroll
  for (int i = 0; i < 8; ++i) {
    size_t grow = rowbase + tr + i;
    if (EPI) {
      if (!l0flag || ((grow & 15) == 0)) {
        int ee = elem[grow >> 4];
        const float* hp = Hbuf + grow * 128 + tc;
        const float* wp = wscL + (size_t)ee * 128 + tc;
        #pragma unroll
        for (int jj = 0; jj < 8; ++jj) acc[i][jj] = fmaf(hp[jj], wp[jj], acc[i][jj]);
      }
    }
    *(float4*)&O[grow * (size_t)oStride + tc]     = make_float4(acc[i][0], acc[i][1], acc[i][2], acc[i][3]);
    *(float4*)&O[grow * (size_t)oStride + tc + 4] = make_float4(acc[i][4], acc[i][5], acc[i][6], acc[i][7]);
  }
}

// One block per node: AGG[n][m][c] = (1/16) * sum_{e->n} h0[send_e, c] * (r2[e]·R3[:, c*4+l(m)]) * sh[e, m]
// Chunked: stage CH edges of (r2, sh, h0) in LDS with all 512 threads, then
// compute all CH edges with zero barriers in between.
constexpr int CH = 16;
__global__ __launch_bounds__(512, 2) void gather_kernel(
    const int* __restrict__ offs, const int* __restrict__ eids,
    const int* __restrict__ ei,
    const float* __restrict__ r2, const float* __restrict__ sh,
    const float* __restrict__ R3P, const float* __restrict__ H,
    float* __restrict__ AGG)
{
  __shared__ float r2s[CH][64];
  __shared__ float shs[CH][16];
  __shared__ float h0s[CH][128];
  int n = blockIdx.x;
  int t = threadIdx.x;
  int l = t >> 7;       // wave-uniform
  int c = t & 127;
  float r3c[64];
  {
    const float4* rp = (const float4*)(R3P + (size_t)t * 64);
    #pragma unroll
    for (int j4 = 0; j4 < 16; ++j4) {
      float4 v = rp[j4];
      r3c[j4*4+0] = v.x; r3c[j4*4+1] = v.y; r3c[j4*4+2] = v.z; r3c[j4*4+3] = v.w;
    }
  }
  float a0=0,a1=0,a2=0,a3=0,a4=0,a5=0,a6=0;
  const int e0 = offs[n], e1 = offs[n+1];
  for (int base = e0; base < e1; base += CH) {
    const int cnt = min(CH, e1 - base);
    // ---- stage chunk (all threads, coalesced, 16-deep MLP) ----
    #pragma unroll
    for (int i = t; i < CH*64; i += 512) {          // r2: 2 iters/thread
      int je = i >> 6;
      if (je < cnt) r2s[je][i & 63] = r2[(size_t)eids[base + je]*64 + (i & 63)];
    }
    #pragma unroll
    for (int i = t; i < CH*128; i += 512) {         // h0: 4 iters/thread
      int je = i >> 7;
      if (je < cnt) {
        int e = eids[base + je];
        h0s[je][i & 127] = H[(size_t)ei[e]*2048 + (i & 127)];
      }
    }
    if (t < CH*16) {                                 // sh
      int je = t >> 4;
      if (je < cnt) shs[je][t & 15] = sh[(size_t)eids[base + je]*16 + (t & 15)];
    }
    __syncthreads();
    // ---- compute chunk, no barriers ----
    for (int j = 0; j < cnt; ++j) {
      float w = 0.f;
      const float4* rr4 = (const float4*)r2s[j];
      #pragma unroll
      for (int j4 = 0; j4 < 16; ++j4) {
        float4 rr = rr4[j4];
        w = fmaf(rr.x, r3c[j4*4+0], w);
        w = fmaf(rr.y, r3c[j4*4+1], w);
        w = fmaf(rr.z, r3c[j4*4+2], w);
        w = fmaf(rr.w, r3c[j4*4+3], w);
      }
      float wh = w * h0s[j][c];
      const float* sj = shs[j];
      if (l == 0) {
        a0 = fmaf(wh, sj[0], a0);
      } else if (l == 1) {
        a0 = fmaf(wh, sj[1], a0); a1 = fmaf(wh, sj[2], a1); a2 = fmaf(wh, sj[3], a2);
      } else if (l == 2) {
        a0 = fmaf(wh, sj[4], a0); a1 = fmaf(wh, sj[5], a1); a2 = fmaf(wh, sj[6], a2);
        a3 = fmaf(wh, sj[7], a3); a4 = fmaf(wh, sj[8], a4);
      } else {
        a0 = fmaf(wh, sj[9], a0);  a1 = fmaf(wh, sj[10], a1); a2 = fmaf(wh, sj[11], a2);
        a3 = fmaf(wh, sj[12], a3); a4 = fmaf(wh, sj[13], a4); a5 = fmaf(wh, sj[14], a5);
        a6 = fmaf(wh, sj[15], a6);
      }
    }
    __syncthreads();
  }
  const float inv16 = 0.0625f;
  size_t baseo = (size_t)n * 2048 + c;
  if (l == 0) {
    AGG[baseo] = a0 * inv16;
  } else if (l == 1) {
    AGG[baseo + 1*128] = a0*inv16; AGG[baseo + 2*128] = a1*inv16; AGG[baseo + 3*128] = a2*inv16;
  } else if (l == 2) {
    AGG[baseo + 4*128] = a0*inv16; AGG[baseo + 5*128] = a1*inv16; AGG[baseo + 6*128] = a2*inv16;
    AGG[baseo + 7*128] = a3*inv16; AGG[baseo + 8*128] = a4*inv16;
  } else {
    AGG[baseo + 9*128]  = a0*inv16; AGG[baseo + 10*128] = a1*inv16; AGG[baseo + 11*128] = a2*inv16;
    AGG[baseo + 12*128] = a3*inv16; AGG[baseo + 13*128] = a4*inv16; AGG[baseo + 14*128] = a5*inv16;
    AGG[baseo + 15*128] = a6*inv16;
  }
}

__global__ __launch_bounds__(256) void scale_kernel(const float* __restrict__ M,
                                                    const int* __restrict__ elem,
                                                    const float* __restrict__ wprodL,
                                                    float* __restrict__ scale) {
  int i = blockIdx.x * 256 + threadIdx.x;  // n*128 + c
  int n = i >> 7, c = i & 127;
  float s = M[(size_t)n * 2048 + c];
  const float* co = wprodL + ((size_t)elem[n] * 128 + c) * 3;
  scale[i] = co[0] + s * (co[1] + s * co[2]);
}

__global__ __launch_bounds__(64) void readout_kernel(const float* __restrict__ F,
                                                     const float* __restrict__ ro0,
                                                     const float* __restrict__ ro1,
                                                     const float* __restrict__ ro2,
                                                     float* __restrict__ out, int layer) {
  int n = blockIdx.x; int t = threadIdx.x;
  const float* fr = F + (size_t)n * 2048;   // feats[n][0][:]
  float f0 = fr[t], f1 = fr[t + 64];
  if (layer == 0) {
    float v = f0 * ro0[t] + f1 * ro0[t + 64];
    #pragma unroll
    for (int m = 32; m > 0; m >>= 1) v += __shfl_xor(v, m, 64);
    if (t == 0) out[n] = v;
  } else {
    float acc = 0.f;
    for (int h = 0; h < 16; ++h) {
      float p = f0 * ro1[t*16 + h] + f1 * ro1[(t + 64)*16 + h];
      #pragma unroll
      for (int m = 32; m > 0; m >>= 1) p += __shfl_xor(p, m, 64);
      acc = fmaf(silu_f(p), ro2[h], acc);
    }
    if (t == 0) out[n] += acc;
  }
}

extern "C" void kernel_launch(void* const* d_in, const int* in_sizes, int n_in,
                              void* d_out, int out_size, void* d_ws, size_t ws_size,
                              hipStream_t stream) {
  (void)in_sizes; (void)n_in; (void)out_size;
  const float* positions = (const float*)d_in[0];
  const float* node_attrs= (const float*)d_in[1];
  const float* shifts    = (const float*)d_in[2];
  const float* W_embed   = (const float*)d_in[3];
  const float* W_up      = (const float*)d_in[4];
  const float* R_w1      = (const float*)d_in[5];
  const float* R_w2      = (const float*)d_in[6];
  const float* R_w3      = (const float*)d_in[7];
  const float* W_out     = (const float*)d_in[8];
  const float* w_sc      = (const float*)d_in[9];
  const float* w_prod    = (const float*)d_in[10];
  const float* W_plin    = (const float*)d_in[11];
  const float* w_ro0     = (const float*)d_in[12];
  const float* ro_w1     = (const float*)d_in[13];
  const float* ro_w2     = (const float*)d_in[14];
  const int*   ei        = (const int*)d_in[15];
  float* out = (float*)d_out;

  char* ws = (char*)d_ws;
  size_t off = 0;
  auto alloc = [&](size_t nbytes) -> void* {
    void* p = ws + off;
    off += (nbytes + 255) & ~(size_t)255;
    return p;
  };
  const size_t PB = (size_t)kN * 16 * 128 * sizeof(float);  // 67 MB
  float* P0     = (float*)alloc(PB);
  float* P1     = (float*)alloc(PB);
  float* P2     = (float*)alloc(PB);
  float* shb    = (float*)alloc((size_t)kE * 16 * 4);
  float* rbb    = (float*)alloc((size_t)kE * 8 * 4);
  float* r2b    = (float*)alloc((size_t)kE * 64 * 4);
  float* scaleb = (float*)alloc((size_t)kN * 128 * 4);
  float* R3P    = (float*)alloc(64 * 512 * 4);
  int* elemb  = (int*)alloc(kN * 4);
  int* counts = (int*)alloc(kN * 4);
  int* cursor = (int*)alloc(kN * 4);
  int* offsb  = (int*)alloc((kN + 1) * 4);
  int* eidsb  = (int*)alloc((size_t)kE * 4);
  if (off > ws_size) return;  // workspace too small: bail (will fail validation loudly)

  // ---- prep ----
  zero_ints_kernel<<<kN/256, 256, 0, stream>>>(counts, cursor);
  elem_kernel<<<kN/256, 256, 0, stream>>>(node_attrs, elemb);
  init_feats_kernel<<<(kN*128)/256, 256, 0, stream>>>(W_embed, elemb, P0);
  geom_kernel<<<kE/256, 256, 0, stream>>>(positions, shifts, ei, shb, rbb);
  count_kernel<<<kE/256, 256, 0, stream>>>(ei, counts);
  scan_kernel<<<1, 1024, 0, stream>>>(counts, offsb);
  fill_kernel<<<kE/256, 256, 0, stream>>>(ei, offsb, cursor, eidsb);

  // ---- layer 0 (feats nonzero only at m=0 -> strided h-einsum over 8192 rows) ----
  radial_kernel<<<kE/4, 256, 0, stream>>>(rbb, R_w1, R_w2, r2b);
  gemm128_kernel<false,false><<<kN/128, 256, 0, stream>>>(P0, 2048, W_up, P1, 2048,
                                                          nullptr, nullptr, nullptr, nullptr, 0);
  permute_r3_kernel<<<(64*512)/256, 256, 0, stream>>>(R_w3, R3P);
  gather_kernel<<<kN, 512, 0, stream>>>(offsb, eidsb, ei, r2b, shb, R3P, P1, P2);
  gemm128_kernel<false,false><<<(kN*16)/128, 256, 0, stream>>>(P2, 128, W_out, P0, 128,
                                                               nullptr, nullptr, nullptr, nullptr, 0);
  scale_kernel<<<(kN*128)/256, 256, 0, stream>>>(P0, elemb, w_prod, scaleb);
  gemm128_kernel<true,true><<<(kN*16)/128, 256, 0, stream>>>(P0, 128, W_plin, P2, 128,
                                                             scaleb, P1, w_sc, elemb, 1);
  readout_kernel<<<kN, 64, 0, stream>>>(P2, w_ro0, ro_w1, ro_w2, out, 0);

  // ---- layer 1 ----
  radial_kernel<<<kE/4, 256, 0, stream>>>(rbb, R_w1 + 512, R_w2 + 4096, r2b);
  gemm128_kernel<false,false><<<(kN*16)/128, 256, 0, stream>>>(P2, 128, W_up + 16384, P1, 128,
                                                               nullptr, nullptr, nullptr, nullptr, 0);
  permute_r3_kernel<<<(64*512)/256, 256, 0, stream>>>(R_w3 + 32768, R3P);
  gather_kernel<<<kN, 512, 0, stream>>>(offsb, eidsb, ei, r2b, shb, R3P, P1, P0);
  gemm128_kernel<false,false><<<(kN*16)/128, 256, 0, stream>>>(P0, 128, W_out + 16384, P2, 128,
                                                               nullptr, nullptr, nullptr, nullptr, 0);
  scale_kernel<<<(kN*128)/256, 256, 0, stream>>>(P2, elemb, w_prod + 3840, scaleb);
  gemm128_kernel<true,true><<<(kN*16)/128, 256, 0, stream>>>(P2, 128, W_plin + 16384, P0, 128,
                                                             scaleb, P1, w_sc + 1280, elemb, 0);
  readout_kernel<<<kN, 64, 0, stream>>>(P0, w_ro0, ro_w1, ro_w2, out, 1);
}

// Round 3
// 1191.556 us; speedup vs baseline: 1.1863x; 1.0912x over previous
//
#include <hip/hip_runtime.h>
#include <math.h>

constexpr int kN = 8192;
constexpr int kE = 131072;

__device__ __forceinline__ float silu_f(float x) { return x / (1.f + __expf(-x)); }

__global__ __launch_bounds__(256) void zero_ints_kernel(int* __restrict__ a, int* __restrict__ b) {
  int i = blockIdx.x * 256 + threadIdx.x;
  if (i < kN) { a[i] = 0; b[i] = 0; }
}

__global__ __launch_bounds__(256) void elem_kernel(const float* __restrict__ attrs, int* __restrict__ elem) {
  int n = blockIdx.x * 256 + threadIdx.x;
  if (n >= kN) return;
  const float* a = attrs + (size_t)n * 10;
  int best = 0; float bv = a[0];
  #pragma unroll
  for (int z = 1; z < 10; ++z) { float v = a[z]; if (v > bv) { bv = v; best = z; } }
  elem[n] = best;
}

__global__ __launch_bounds__(256) void init_feats_kernel(const float* __restrict__ W_embed,
                                                         const int* __restrict__ elem,
                                                         float* __restrict__ F) {
  int i = blockIdx.x * 256 + threadIdx.x;   // n*128 + c
  int n = i >> 7, c = i & 127;
  F[(size_t)n * 2048 + c] = W_embed[(size_t)elem[n] * 128 + c];
}

__global__ __launch_bounds__(256) void geom_kernel(const float* __restrict__ pos,
                                                   const float* __restrict__ shifts,
                                                   const int* __restrict__ ei,
                                                   float* __restrict__ sh,
                                                   float* __restrict__ rb) {
  int e = blockIdx.x * 256 + threadIdx.x;
  if (e >= kE) return;
  int s = ei[e], r = ei[kE + e];
  float vx = pos[r*3+0] - pos[s*3+0] + shifts[(size_t)e*3+0];
  float vy = pos[r*3+1] - pos[s*3+1] + shifts[(size_t)e*3+1];
  float vz = pos[r*3+2] - pos[s*3+2] + shifts[(size_t)e*3+2];
  float len = sqrtf(vx*vx + vy*vy + vz*vz) + 1e-9f;
  float inv = 1.f / len;
  float x = vx*inv, y = vy*inv, z = vz*inv;
  float x2 = x*x, y2 = y*y, z2 = z*z;
  const float s3  = 1.7320508075688772f;
  const float s5  = 2.2360679774997896f;
  const float s15 = 3.8729833462074170f;
  const float a33 = 2.0916500663351889f;   // 0.25*sqrt(70)
  const float a32 = 10.246950765959598f;   // sqrt(105)
  const float a31 = 1.6201851746019651f;   // 0.25*sqrt(42)
  const float a30 = 1.3228756555322954f;   // 0.5*sqrt(7)
  float4* shp = (float4*)(sh + (size_t)e * 16);
  shp[0] = make_float4(1.f, s3*x, s3*y, s3*z);
  shp[1] = make_float4(s15*x*y, s15*y*z, 0.5f*s5*(3.f*z2 - 1.f), s15*x*z);
  shp[2] = make_float4(0.5f*s15*(x2 - y2), a33*y*(3.f*x2 - y2), a32*x*y*z, a31*y*(5.f*z2 - 1.f));
  shp[3] = make_float4(a30*z*(5.f*z2 - 3.f), a31*x*(5.f*z2 - 1.f), 0.5f*a32*z*(x2 - y2), a33*x*(x2 - 3.f*y2));
  float xr = len * 0.2f;            // r / R_MAX
  float cut = 0.f;
  if (xr < 1.f) {
    float x5 = xr*xr*xr*xr*xr;
    cut = 1.f - 21.f*x5 + 35.f*x5*xr - 15.f*x5*xr*xr;
  }
  float pref = 0.63245553203367587f * cut * inv;   // sqrt(2/5)*cut/r
  const float PI = 3.14159265358979323846f;
  float b[8];
  #pragma unroll
  for (int k = 0; k < 8; ++k) b[k] = pref * sinf((float)(k+1) * PI * xr);
  float4* rbp = (float4*)(rb + (size_t)e * 8);
  rbp[0] = make_float4(b[0], b[1], b[2], b[3]);
  rbp[1] = make_float4(b[4], b[5], b[6], b[7]);
}

__global__ __launch_bounds__(256) void count_kernel(const int* __restrict__ ei, int* __restrict__ counts) {
  int e = blockIdx.x * 256 + threadIdx.x;
  if (e < kE) atomicAdd(&counts[ei[kE + e]], 1);
}

__global__ __launch_bounds__(1024) void scan_kernel(const int* __restrict__ counts, int* __restrict__ offs) {
  __shared__ int tmp[1024];
  int t = threadIdx.x;
  int loc[8]; int s = 0;
  #pragma unroll
  for (int i = 0; i < 8; ++i) { loc[i] = s; s += counts[t*8 + i]; }
  tmp[t] = s;
  __syncthreads();
  for (int d = 1; d < 1024; d <<= 1) {
    int v = (t >= d) ? tmp[t - d] : 0;
    __syncthreads();
    tmp[t] += v;
    __syncthreads();
  }
  int pre = (t == 0) ? 0 : tmp[t - 1];
  #pragma unroll
  for (int i = 0; i < 8; ++i) offs[t*8 + i] = pre + loc[i];
  if (t == 1023) offs[kN] = tmp[1023];
}

__global__ __launch_bounds__(256) void fill_kernel(const int* __restrict__ ei, const int* __restrict__ offs,
                                                   int* __restrict__ cursor, int* __restrict__ eids) {
  int e = blockIdx.x * 256 + threadIdx.x;
  if (e >= kE) return;
  int r = ei[kE + e];
  int pos = atomicAdd(&cursor[r], 1);
  eids[offs[r] + pos] = e;
}

__global__ __launch_bounds__(256) void radial_kernel(const float* __restrict__ rb,
                                                     const float* __restrict__ W1,
                                                     const float* __restrict__ W2,
                                                     float* __restrict__ r2) {
  __shared__ float W1s[8*64];
  __shared__ float W2s[64*64];
  __shared__ float r1s[4][64];
  int tid = threadIdx.x;
  for (int i = tid; i < 512; i += 256) W1s[i] = W1[i];
  for (int i = tid; i < 4096; i += 256) W2s[i] = W2[i];
  __syncthreads();
  int g = tid >> 6, j = tid & 63;
  int e = blockIdx.x * 4 + g;
  const float* rbe = rb + (size_t)e * 8;
  float v = 0.f;
  #pragma unroll
  for (int i = 0; i < 8; ++i) v = fmaf(rbe[i], W1s[i*64 + j], v);
  r1s[g][j] = silu_f(v);
  __syncthreads();
  float u = 0.f;
  #pragma unroll
  for (int i = 0; i < 64; ++i) u = fmaf(r1s[g][i], W2s[i*64 + j], u);
  r2[(size_t)e * 64 + j] = silu_f(u);
}

__global__ __launch_bounds__(256) void permute_r3_kernel(const float* __restrict__ R3L, float* __restrict__ R3P) {
  int i = blockIdx.x * 256 + threadIdx.x;   // t*64 + j, t = l*128 + c
  int j = i & 63, t = i >> 6;
  int l = t >> 7, c = t & 127;
  R3P[i] = R3L[j * 512 + (c << 2) + l];
}

// Out[row, d] = sum_c A[row*aStride + c] * W[c*128 + d]   (K = 128, Ncols = 128)
// SCALED: A element (row, c) multiplied by scaleBuf[(row>>4)*128 + c]
// EPI: Out += H[row*128 + d] * wscL[elem[row>>4]*128 + d]  (only rows with row%16==0 if l0flag)
template<bool SCALED, bool EPI>
__global__ __launch_bounds__(256) void gemm128_kernel(
    const float* __restrict__ A, int aStride,
    const float* __restrict__ W,
    float* __restrict__ O, int oStride,
    const float* __restrict__ scaleBuf,
    const float* __restrict__ Hbuf,
    const float* __restrict__ wscL,
    const int* __restrict__ elem,
    int l0flag)
{
  __shared__ float As[128*132];   // k-major, +4 pad
  __shared__ float Bs[128*128];
  const int tid = threadIdx.x;
  const size_t rowbase = (size_t)blockIdx.x * 128;
  {
    int k0 = tid >> 5, c4 = (tid & 31) * 4;
    #pragma unroll
    for (int it = 0; it < 16; ++it) {
      int kk = k0 + it*8;
      *(float4*)&Bs[kk*128 + c4] = *(const float4*)&W[kk*128 + c4];
    }
  }
  {
    int kk = tid & 31, rr = tid >> 5;
    #pragma unroll
    for (int it = 0; it < 16; ++it) {
      int r = rr + it*8;
      size_t grow = rowbase + r;
      const float* ap = A + grow * (size_t)aStride;
      #pragma unroll
      for (int q = 0; q < 4; ++q) {
        int k = kk + 32*q;
        float v = ap[k];
        if (SCALED) v *= scaleBuf[(grow >> 4) * 128 + k];
        As[k*132 + r] = v;
      }
    }
  }
  __syncthreads();
  const int tr = (tid >> 4) * 8, tc = (tid & 15) * 8;
  float acc[8][8] = {};
  #pragma unroll 2
  for (int k = 0; k < 128; ++k) {
    float4 A0 = *(const float4*)&As[k*132 + tr];
    float4 A1 = *(const float4*)&As[k*132 + tr + 4];
    float4 B0 = *(const float4*)&Bs[k*128 + tc];
    float4 B1 = *(const float4*)&Bs[k*128 + tc + 4];
    float av[8] = {A0.x,A0.y,A0.z,A0.w,A1.x,A1.y,A1.z,A1.w};
    float bv[8] = {B0.x,B0.y,B0.z,B0.w,B1.x,B1.y,B1.z,B1.w};
    #pragma unroll
    for (int i = 0; i < 8; ++i) {
      #pragma unroll
      for (int jj = 0; jj < 8; ++jj)
        acc[i][jj] = fmaf(av[i], bv[jj], acc[i][jj]);
    }
  }
  #pragma unroll
  for (int i = 0; i < 8; ++i) {
    size_t grow = rowbase + tr + i;
    if (EPI) {
      if (!l0flag || ((grow & 15) == 0)) {
        int ee = elem[grow >> 4];
        const float* hp = Hbuf + grow * 128 + tc;
        const float* wp = wscL + (size_t)ee * 128 + tc;
        #pragma unroll
        for (int jj = 0; jj < 8; ++jj) acc[i][jj] = fmaf(hp[jj], wp[jj], acc[i][jj]);
      }
    }
    *(float4*)&O[grow * (size_t)oStride + tc]     = make_float4(acc[i][0], acc[i][1], acc[i][2], acc[i][3]);
    *(float4*)&O[grow * (size_t)oStride + tc + 4] = make_float4(acc[i][4], acc[i][5], acc[i][6], acc[i][7]);
  }
}

// One block per node: AGG[n][m][c] = (1/16) * sum_{e->n} h0[send_e, c] * (r2[e]·R3[:, c*4+l(m)]) * sh[e, m]
// Chunked LDS staging (float4) + per-thread R3 column PINNED in VGPRs.
constexpr int CH = 16;
__global__ __launch_bounds__(512, 2) void gather_kernel(
    const int* __restrict__ offs, const int* __restrict__ eids,
    const int* __restrict__ ei,
    const float* __restrict__ r2, const float* __restrict__ sh,
    const float* __restrict__ R3P, const float* __restrict__ H,
    float* __restrict__ AGG)
{
  __shared__ float r2s[CH][64];
  __shared__ float shs[CH][16];
  __shared__ float h0s[CH][128];
  int n = blockIdx.x;
  int t = threadIdx.x;
  int l = t >> 7;       // wave-uniform
  int c = t & 127;
  float r3c[64];
  {
    const float4* rp = (const float4*)(R3P + (size_t)t * 64);
    #pragma unroll
    for (int j4 = 0; j4 < 16; ++j4) {
      float4 v = rp[j4];
      r3c[j4*4+0] = v.x; r3c[j4*4+1] = v.y; r3c[j4*4+2] = v.z; r3c[j4*4+3] = v.w;
    }
  }
  // Pin the column into VGPRs: opaque asm def cannot be rematerialized, so
  // the allocator must keep all 64 values register-resident across the loop.
  #pragma unroll
  for (int i = 0; i < 64; ++i) asm volatile("" : "+v"(r3c[i]));

  float a0=0,a1=0,a2=0,a3=0,a4=0,a5=0,a6=0;
  const int e0 = offs[n], e1 = offs[n+1];
  for (int base = e0; base < e1; base += CH) {
    const int cnt = min(CH, e1 - base);
    // ---- stage chunk with float4 writes ----
    if (t < 256) {                     // r2: CH*64 floats = 256 float4
      int je = t >> 4;
      if (je < cnt) {
        int e = eids[base + je];
        *(float4*)&r2s[je][(t & 15) * 4] = *(const float4*)&r2[(size_t)e*64 + (t & 15)*4];
      }
    } else if (t < 320) {              // sh: CH*16 floats = 64 float4
      int tt = t - 256;
      int je = tt >> 2;
      if (je < cnt) {
        int e = eids[base + je];
        *(float4*)&shs[je][(tt & 3) * 4] = *(const float4*)&sh[(size_t)e*16 + (tt & 3)*4];
      }
    }
    {                                  // h0: CH*128 floats = 512 float4
      int je = t >> 5;
      if (je < cnt) {
        int e = eids[base + je];
        int s = ei[e];
        *(float4*)&h0s[je][(t & 31) * 4] = *(const float4*)&H[(size_t)s*2048 + (t & 31)*4];
      }
    }
    __syncthreads();
    // ---- compute chunk, no barriers ----
    for (int j = 0; j < cnt; ++j) {
      float w = 0.f;
      const float4* rr4 = (const float4*)r2s[j];
      #pragma unroll
      for (int j4 = 0; j4 < 16; ++j4) {
        float4 rr = rr4[j4];
        w = fmaf(rr.x, r3c[j4*4+0], w);
        w = fmaf(rr.y, r3c[j4*4+1], w);
        w = fmaf(rr.z, r3c[j4*4+2], w);
        w = fmaf(rr.w, r3c[j4*4+3], w);
      }
      float wh = w * h0s[j][c];
      const float* sj = shs[j];
      if (l == 0) {
        a0 = fmaf(wh, sj[0], a0);
      } else if (l == 1) {
        a0 = fmaf(wh, sj[1], a0); a1 = fmaf(wh, sj[2], a1); a2 = fmaf(wh, sj[3], a2);
      } else if (l == 2) {
        a0 = fmaf(wh, sj[4], a0); a1 = fmaf(wh, sj[5], a1); a2 = fmaf(wh, sj[6], a2);
        a3 = fmaf(wh, sj[7], a3); a4 = fmaf(wh, sj[8], a4);
      } else {
        a0 = fmaf(wh, sj[9], a0);  a1 = fmaf(wh, sj[10], a1); a2 = fmaf(wh, sj[11], a2);
        a3 = fmaf(wh, sj[12], a3); a4 = fmaf(wh, sj[13], a4); a5 = fmaf(wh, sj[14], a5);
        a6 = fmaf(wh, sj[15], a6);
      }
    }
    __syncthreads();
  }
  const float inv16 = 0.0625f;
  size_t baseo = (size_t)n * 2048 + c;
  if (l == 0) {
    AGG[baseo] = a0 * inv16;
  } else if (l == 1) {
    AGG[baseo + 1*128] = a0*inv16; AGG[baseo + 2*128] = a1*inv16; AGG[baseo + 3*128] = a2*inv16;
  } else if (l == 2) {
    AGG[baseo + 4*128] = a0*inv16; AGG[baseo + 5*128] = a1*inv16; AGG[baseo + 6*128] = a2*inv16;
    AGG[baseo + 7*128] = a3*inv16; AGG[baseo + 8*128] = a4*inv16;
  } else {
    AGG[baseo + 9*128]  = a0*inv16; AGG[baseo + 10*128] = a1*inv16; AGG[baseo + 11*128] = a2*inv16;
    AGG[baseo + 12*128] = a3*inv16; AGG[baseo + 13*128] = a4*inv16; AGG[baseo + 14*128] = a5*inv16;
    AGG[baseo + 15*128] = a6*inv16;
  }
}

__global__ __launch_bounds__(256) void scale_kernel(const float* __restrict__ M,
                                                    const int* __restrict__ elem,
                                                    const float* __restrict__ wprodL,
                                                    float* __restrict__ scale) {
  int i = blockIdx.x * 256 + threadIdx.x;  // n*128 + c
  int n = i >> 7, c = i & 127;
  float s = M[(size_t)n * 2048 + c];
  const float* co = wprodL + ((size_t)elem[n] * 128 + c) * 3;
  scale[i] = co[0] + s * (co[1] + s * co[2]);
}

__global__ __launch_bounds__(64) void readout_kernel(const float* __restrict__ F,
                                                     const float* __restrict__ ro0,
                                                     const float* __restrict__ ro1,
                                                     const float* __restrict__ ro2,
                                                     float* __restrict__ out, int layer) {
  int n = blockIdx.x; int t = threadIdx.x;
  const float* fr = F + (size_t)n * 2048;   // feats[n][0][:]
  float f0 = fr[t], f1 = fr[t + 64];
  if (layer == 0) {
    float v = f0 * ro0[t] + f1 * ro0[t + 64];
    #pragma unroll
    for (int m = 32; m > 0; m >>= 1) v += __shfl_xor(v, m, 64);
    if (t == 0) out[n] = v;
  } else {
    float acc = 0.f;
    for (int h = 0; h < 16; ++h) {
      float p = f0 * ro1[t*16 + h] + f1 * ro1[(t + 64)*16 + h];
      #pragma unroll
      for (int m = 32; m > 0; m >>= 1) p += __shfl_xor(p, m, 64);
      acc = fmaf(silu_f(p), ro2[h], acc);
    }
    if (t == 0) out[n] += acc;
  }
}

extern "C" void kernel_launch(void* const* d_in, const int* in_sizes, int n_in,
                              void* d_out, int out_size, void* d_ws, size_t ws_size,
                              hipStream_t stream) {
  (void)in_sizes; (void)n_in; (void)out_size;
  const float* positions = (const float*)d_in[0];
  const float* node_attrs= (const float*)d_in[1];
  const float* shifts    = (const float*)d_in[2];
  const float* W_embed   = (const float*)d_in[3];
  const float* W_up      = (const float*)d_in[4];
  const float* R_w1      = (const float*)d_in[5];
  const float* R_w2      = (const float*)d_in[6];
  const float* R_w3      = (const float*)d_in[7];
  const float* W_out     = (const float*)d_in[8];
  const float* w_sc      = (const float*)d_in[9];
  const float* w_prod    = (const float*)d_in[10];
  const float* W_plin    = (const float*)d_in[11];
  const float* w_ro0     = (const float*)d_in[12];
  const float* ro_w1     = (const float*)d_in[13];
  const float* ro_w2     = (const float*)d_in[14];
  const int*   ei        = (const int*)d_in[15];
  float* out = (float*)d_out;

  char* ws = (char*)d_ws;
  size_t off = 0;
  auto alloc = [&](size_t nbytes) -> void* {
    void* p = ws + off;
    off += (nbytes + 255) & ~(size_t)255;
    return p;
  };
  const size_t PB = (size_t)kN * 16 * 128 * sizeof(float);  // 67 MB
  float* P0     = (float*)alloc(PB);
  float* P1     = (float*)alloc(PB);
  float* P2     = (float*)alloc(PB);
  float* shb    = (float*)alloc((size_t)kE * 16 * 4);
  float* rbb    = (float*)alloc((size_t)kE * 8 * 4);
  float* r2b    = (float*)alloc((size_t)kE * 64 * 4);
  float* scaleb = (float*)alloc((size_t)kN * 128 * 4);
  float* R3P    = (float*)alloc(64 * 512 * 4);
  int* elemb  = (int*)alloc(kN * 4);
  int* counts = (int*)alloc(kN * 4);
  int* cursor = (int*)alloc(kN * 4);
  int* offsb  = (int*)alloc((kN + 1) * 4);
  int* eidsb  = (int*)alloc((size_t)kE * 4);
  if (off > ws_size) return;  // workspace too small: bail (will fail validation loudly)

  // ---- prep ----
  zero_ints_kernel<<<kN/256, 256, 0, stream>>>(counts, cursor);
  elem_kernel<<<kN/256, 256, 0, stream>>>(node_attrs, elemb);
  init_feats_kernel<<<(kN*128)/256, 256, 0, stream>>>(W_embed, elemb, P0);
  geom_kernel<<<kE/256, 256, 0, stream>>>(positions, shifts, ei, shb, rbb);
  count_kernel<<<kE/256, 256, 0, stream>>>(ei, counts);
  scan_kernel<<<1, 1024, 0, stream>>>(counts, offsb);
  fill_kernel<<<kE/256, 256, 0, stream>>>(ei, offsb, cursor, eidsb);

  // ---- layer 0 (feats nonzero only at m=0 -> strided h-einsum over 8192 rows) ----
  radial_kernel<<<kE/4, 256, 0, stream>>>(rbb, R_w1, R_w2, r2b);
  gemm128_kernel<false,false><<<kN/128, 256, 0, stream>>>(P0, 2048, W_up, P1, 2048,
                                                          nullptr, nullptr, nullptr, nullptr, 0);
  permute_r3_kernel<<<(64*512)/256, 256, 0, stream>>>(R_w3, R3P);
  gather_kernel<<<kN, 512, 0, stream>>>(offsb, eidsb, ei, r2b, shb, R3P, P1, P2);
  gemm128_kernel<false,false><<<(kN*16)/128, 256, 0, stream>>>(P2, 128, W_out, P0, 128,
                                                               nullptr, nullptr, nullptr, nullptr, 0);
  scale_kernel<<<(kN*128)/256, 256, 0, stream>>>(P0, elemb, w_prod, scaleb);
  gemm128_kernel<true,true><<<(kN*16)/128, 256, 0, stream>>>(P0, 128, W_plin, P2, 128,
                                                             scaleb, P1, w_sc, elemb, 1);
  readout_kernel<<<kN, 64, 0, stream>>>(P2, w_ro0, ro_w1, ro_w2, out, 0);

  // ---- layer 1 ----
  radial_kernel<<<kE/4, 256, 0, stream>>>(rbb, R_w1 + 512, R_w2 + 4096, r2b);
  gemm128_kernel<false,false><<<(kN*16)/128, 256, 0, stream>>>(P2, 128, W_up + 16384, P1, 128,
                                                               nullptr, nullptr, nullptr, nullptr, 0);
  permute_r3_kernel<<<(64*512)/256, 256, 0, stream>>>(R_w3 + 32768, R3P);
  gather_kernel<<<kN, 512, 0, stream>>>(offsb, eidsb, ei, r2b, shb, R3P, P1, P0);
  gemm128_kernel<false,false><<<(kN*16)/128, 256, 0, stream>>>(P0, 128, W_out + 16384, P2, 128,
                                                               nullptr, nullptr, nullptr, nullptr, 0);
  scale_kernel<<<(kN*128)/256, 256, 0, stream>>>(P2, elemb, w_prod + 3840, scaleb);
  gemm128_kernel<true,true><<<(kN*16)/128, 256, 0, stream>>>(P2, 128, W_plin + 16384, P0, 128,
                                                             scaleb, P1, w_sc + 1280, elemb, 0);
  readout_kernel<<<kN, 64, 0, stream>>>(P0, w_ro0, ro_w1, ro_w2, out, 1);
}

// Round 5
// 580.011 us; speedup vs baseline: 2.4370x; 2.0544x over previous
//
#include <hip/hip_runtime.h>
#include <math.h>

constexpr int kN = 8192;
constexpr int kE = 131072;
constexpr int kHalfN = 4096;
constexpr int kWbTiles = 544;                 // 544*128 = 69632 rows >= half-span (~65536)
constexpr int kWbRows  = kWbTiles * 128;

typedef short bf16x8 __attribute__((ext_vector_type(8)));
typedef float f32x4 __attribute__((ext_vector_type(4)));
typedef unsigned short ushort_t;
typedef unsigned int uint_t;

__device__ __forceinline__ float silu_f(float x) { return x / (1.f + __expf(-x)); }

__device__ __forceinline__ ushort_t f2b(float f) {
  uint_t x = __float_as_uint(f);
  uint_t r = (x + 0x7fffu + ((x >> 16) & 1u)) >> 16;
  return (ushort_t)r;
}
__device__ __forceinline__ float b2f(ushort_t u) {
  return __uint_as_float(((uint_t)u) << 16);
}

__global__ __launch_bounds__(256) void zero_ints_kernel(int* __restrict__ a, int* __restrict__ b) {
  int i = blockIdx.x * 256 + threadIdx.x;
  if (i < kN) { a[i] = 0; b[i] = 0; }
}

__global__ __launch_bounds__(256) void elem_kernel(const float* __restrict__ attrs, int* __restrict__ elem) {
  int n = blockIdx.x * 256 + threadIdx.x;
  if (n >= kN) return;
  const float* a = attrs + (size_t)n * 10;
  int best = 0; float bv = a[0];
  #pragma unroll
  for (int z = 1; z < 10; ++z) { float v = a[z]; if (v > bv) { bv = v; best = z; } }
  elem[n] = best;
}

__global__ __launch_bounds__(256) void init_feats_kernel(const float* __restrict__ W_embed,
                                                         const int* __restrict__ elem,
                                                         ushort_t* __restrict__ F) {
  int i = blockIdx.x * 256 + threadIdx.x;   // n*128 + c
  int n = i >> 7, c = i & 127;
  F[(size_t)n * 2048 + c] = f2b(W_embed[(size_t)elem[n] * 128 + c]);
}

__global__ __launch_bounds__(256) void geom_kernel(const float* __restrict__ pos,
                                                   const float* __restrict__ shifts,
                                                   const int* __restrict__ ei,
                                                   float* __restrict__ sh,
                                                   float* __restrict__ rb) {
  int e = blockIdx.x * 256 + threadIdx.x;
  if (e >= kE) return;
  int s = ei[e], r = ei[kE + e];
  float vx = pos[r*3+0] - pos[s*3+0] + shifts[(size_t)e*3+0];
  float vy = pos[r*3+1] - pos[s*3+1] + shifts[(size_t)e*3+1];
  float vz = pos[r*3+2] - pos[s*3+2] + shifts[(size_t)e*3+2];
  float len = sqrtf(vx*vx + vy*vy + vz*vz) + 1e-9f;
  float inv = 1.f / len;
  float x = vx*inv, y = vy*inv, z = vz*inv;
  float x2 = x*x, y2 = y*y, z2 = z*z;
  const float s3  = 1.7320508075688772f;
  const float s5  = 2.2360679774997896f;
  const float s15 = 3.8729833462074170f;
  const float a33 = 2.0916500663351889f;
  const float a32 = 10.246950765959598f;
  const float a31 = 1.6201851746019651f;
  const float a30 = 1.3228756555322954f;
  float4* shp = (float4*)(sh + (size_t)e * 16);
  shp[0] = make_float4(1.f, s3*x, s3*y, s3*z);
  shp[1] = make_float4(s15*x*y, s15*y*z, 0.5f*s5*(3.f*z2 - 1.f), s15*x*z);
  shp[2] = make_float4(0.5f*s15*(x2 - y2), a33*y*(3.f*x2 - y2), a32*x*y*z, a31*y*(5.f*z2 - 1.f));
  shp[3] = make_float4(a30*z*(5.f*z2 - 3.f), a31*x*(5.f*z2 - 1.f), 0.5f*a32*z*(x2 - y2), a33*x*(x2 - 3.f*y2));
  float xr = len * 0.2f;
  float cut = 0.f;
  if (xr < 1.f) {
    float x5 = xr*xr*xr*xr*xr;
    cut = 1.f - 21.f*x5 + 35.f*x5*xr - 15.f*x5*xr*xr;
  }
  float pref = 0.63245553203367587f * cut * inv;
  const float PI = 3.14159265358979323846f;
  float b[8];
  #pragma unroll
  for (int k = 0; k < 8; ++k) b[k] = pref * sinf((float)(k+1) * PI * xr);
  float4* rbp = (float4*)(rb + (size_t)e * 8);
  rbp[0] = make_float4(b[0], b[1], b[2], b[3]);
  rbp[1] = make_float4(b[4], b[5], b[6], b[7]);
}

__global__ __launch_bounds__(256) void count_kernel(const int* __restrict__ ei, int* __restrict__ counts) {
  int e = blockIdx.x * 256 + threadIdx.x;
  if (e < kE) atomicAdd(&counts[ei[kE + e]], 1);
}

__global__ __launch_bounds__(1024) void scan_kernel(const int* __restrict__ counts, int* __restrict__ offs) {
  __shared__ int tmp[1024];
  int t = threadIdx.x;
  int loc[8]; int s = 0;
  #pragma unroll
  for (int i = 0; i < 8; ++i) { loc[i] = s; s += counts[t*8 + i]; }
  tmp[t] = s;
  __syncthreads();
  for (int d = 1; d < 1024; d <<= 1) {
    int v = (t >= d) ? tmp[t - d] : 0;
    __syncthreads();
    tmp[t] += v;
    __syncthreads();
  }
  int pre = (t == 0) ? 0 : tmp[t - 1];
  #pragma unroll
  for (int i = 0; i < 8; ++i) offs[t*8 + i] = pre + loc[i];
  if (t == 1023) offs[kN] = tmp[1023];
}

__global__ __launch_bounds__(256) void fill_kernel(const int* __restrict__ ei, const int* __restrict__ offs,
                                                   int* __restrict__ cursor, int* __restrict__ eids) {
  int e = blockIdx.x * 256 + threadIdx.x;
  if (e >= kE) return;
  int r = ei[kE + e];
  int pos = atomicAdd(&cursor[r], 1);
  eids[offs[r] + pos] = e;
}

__global__ __launch_bounds__(256) void radial_kernel(const float* __restrict__ rb,
                                                     const float* __restrict__ W1,
                                                     const float* __restrict__ W2,
                                                     ushort_t* __restrict__ r2) {
  __shared__ float W1s[8*64];
  __shared__ float W2s[64*64];
  __shared__ float r1s[4][64];
  int tid = threadIdx.x;
  for (int i = tid; i < 512; i += 256) W1s[i] = W1[i];
  for (int i = tid; i < 4096; i += 256) W2s[i] = W2[i];
  __syncthreads();
  int g = tid >> 6, j = tid & 63;
  int e = blockIdx.x * 4 + g;
  const float* rbe = rb + (size_t)e * 8;
  float v = 0.f;
  #pragma unroll
  for (int i = 0; i < 8; ++i) v = fmaf(rbe[i], W1s[i*64 + j], v);
  r1s[g][j] = silu_f(v);
  __syncthreads();
  float u = 0.f;
  #pragma unroll
  for (int i = 0; i < 64; ++i) u = fmaf(r1s[g][i], W2s[i*64 + j], u);
  r2[(size_t)e * 64 + j] = f2b(silu_f(u));
}

// WT[d][c] = W[c][d], bf16.  (128x128)
__global__ __launch_bounds__(256) void transpose_w_kernel(const float* __restrict__ W, ushort_t* __restrict__ WT) {
  int i = blockIdx.x * 256 + threadIdx.x;   // d*128 + c
  int d = i >> 7, c = i & 127;
  WT[i] = f2b(W[c*128 + d]);
}

// R3T[t][j] = R_w3[j][t], bf16.  t = c*4+l in [0,512), j in [0,64)
__global__ __launch_bounds__(256) void transpose_r3_kernel(const float* __restrict__ R3, ushort_t* __restrict__ R3T) {
  int i = blockIdx.x * 256 + threadIdx.x;   // t*64 + j
  int t = i >> 6, j = i & 63;
  R3T[i] = f2b(R3[j*512 + t]);
}

// MFMA GEMM (K=128): O[row, col] = sum_k A[row,k] * BT[col,k].
// SCALED: A(row,k) *= scaleBuf[(row>>4)*128 + k].
// EPI: O += H[row*128+col]*wscL[elem[row>>4]*128+col]; L0 limits EPI to row%16==0.
template<bool SCALED, bool EPI, bool L0>
__global__ __launch_bounds__(256) void mgemm_kernel(
    const ushort_t* __restrict__ A, size_t aStride,
    const ushort_t* __restrict__ BT,
    ushort_t* __restrict__ O, size_t oStride,
    const float* __restrict__ scaleBuf,
    const ushort_t* __restrict__ Hbuf,
    const float* __restrict__ wscL,
    const int* __restrict__ elem)
{
  __shared__ ushort_t As[128][136];
  __shared__ ushort_t Bs[128][136];
  const int tid = threadIdx.x;
  const size_t rowbase = (size_t)blockIdx.x * 128;

  for (int idx = tid * 8; idx < 128 * 128; idx += 256 * 8) {
    int r = idx >> 7, k = idx & 127;
    *(int4*)&Bs[r][k] = *(const int4*)&BT[(size_t)r * 128 + k];
  }
  for (int idx = tid * 8; idx < 128 * 128; idx += 256 * 8) {
    int r = idx >> 7, k = idx & 127;
    size_t grow = rowbase + r;
    const ushort_t* ap = A + grow * aStride + k;
    if (SCALED) {
      const float* sp = scaleBuf + (grow >> 4) * 128 + k;
      uint_t u[4];
      #pragma unroll
      for (int q = 0; q < 4; ++q) {
        ushort_t lo = f2b(b2f(ap[2*q])   * sp[2*q]);
        ushort_t hi = f2b(b2f(ap[2*q+1]) * sp[2*q+1]);
        u[q] = (uint_t)lo | ((uint_t)hi << 16);
      }
      *(int4*)&As[r][k] = make_int4((int)u[0], (int)u[1], (int)u[2], (int)u[3]);
    } else {
      *(int4*)&As[r][k] = *(const int4*)ap;
    }
  }
  __syncthreads();

  const int lane = tid & 63, wv = tid >> 6;
  const int wr = (wv >> 1) * 64, wc = (wv & 1) * 64;
  const int fr = lane & 15;
  const int kg = (lane >> 4) * 8;
  f32x4 acc[4][4] = {};
  #pragma unroll
  for (int ks = 0; ks < 4; ++ks) {
    const int k0 = ks * 32 + kg;
    bf16x8 af[4], bfr[4];
    #pragma unroll
    for (int i = 0; i < 4; ++i) af[i]  = *(const bf16x8*)&As[wr + i*16 + fr][k0];
    #pragma unroll
    for (int j = 0; j < 4; ++j) bfr[j] = *(const bf16x8*)&Bs[wc + j*16 + fr][k0];
    #pragma unroll
    for (int i = 0; i < 4; ++i)
      #pragma unroll
      for (int j = 0; j < 4; ++j)
        acc[i][j] = __builtin_amdgcn_mfma_f32_16x16x32_bf16(af[i], bfr[j], acc[i][j], 0, 0, 0);
  }

  const int dcol = lane & 15, drow4 = (lane >> 4) * 4;
  #pragma unroll
  for (int i = 0; i < 4; ++i) {
    #pragma unroll
    for (int j = 0; j < 4; ++j) {
      int col = wc + j*16 + dcol;
      #pragma unroll
      for (int r = 0; r < 4; ++r) {
        int row = wr + i*16 + drow4 + r;
        size_t grow = rowbase + row;
        float v = acc[i][j][r];
        if (EPI) {
          if (!L0 || ((grow & 15) == 0)) {
            int ee = elem[grow >> 4];
            v += b2f(Hbuf[grow * 128 + col]) * wscL[(size_t)ee * 128 + col];
          }
        }
        O[grow * oStride + col] = f2b(v);
      }
    }
  }
}

// w-GEMM, CSR-ordered: wb[local_row][t] = sum_k r2[eids[halfStart+local_row]][k] * R3T[t][k]
// local_row in [0, kWbRows), K=64, cols 512 over grid.y=4.
__global__ __launch_bounds__(256) void wgemm_kernel(
    const ushort_t* __restrict__ r2, const int* __restrict__ eids,
    const int* __restrict__ offs, int nb0,
    const ushort_t* __restrict__ R3T, ushort_t* __restrict__ wb)
{
  __shared__ ushort_t As[128][72];
  __shared__ ushort_t Bs[128][72];
  const int tid = threadIdx.x;
  const int rowbase = blockIdx.x * 128;
  const int colbase = blockIdx.y * 128;
  const int halfStart = offs[nb0];
  const int halfEnd   = offs[nb0 + kHalfN];

  for (int idx = tid * 8; idx < 128 * 64; idx += 256 * 8) {
    int r = idx >> 6, k = idx & 63;
    *(int4*)&Bs[r][k] = *(const int4*)&R3T[(size_t)(colbase + r) * 64 + k];
  }
  for (int idx = tid * 8; idx < 128 * 64; idx += 256 * 8) {
    int r = idx >> 6, k = idx & 63;
    int ii = halfStart + rowbase + r;
    int iic = ii < halfEnd ? ii : (halfEnd - 1);
    if (iic < 0) iic = 0;
    int e = eids[iic];
    *(int4*)&As[r][k] = *(const int4*)&r2[(size_t)e * 64 + k];
  }
  __syncthreads();

  const int lane = tid & 63, wv = tid >> 6;
  const int wr = (wv >> 1) * 64, wc = (wv & 1) * 64;
  const int fr = lane & 15;
  const int kg = (lane >> 4) * 8;
  f32x4 acc[4][4] = {};
  #pragma unroll
  for (int ks = 0; ks < 2; ++ks) {
    const int k0 = ks * 32 + kg;
    bf16x8 af[4], bfr[4];
    #pragma unroll
    for (int i = 0; i < 4; ++i) af[i]  = *(const bf16x8*)&As[wr + i*16 + fr][k0];
    #pragma unroll
    for (int j = 0; j < 4; ++j) bfr[j] = *(const bf16x8*)&Bs[wc + j*16 + fr][k0];
    #pragma unroll
    for (int i = 0; i < 4; ++i)
      #pragma unroll
      for (int j = 0; j < 4; ++j)
        acc[i][j] = __builtin_amdgcn_mfma_f32_16x16x32_bf16(af[i], bfr[j], acc[i][j], 0, 0, 0);
  }

  const int dcol = lane & 15, drow4 = (lane >> 4) * 4;
  #pragma unroll
  for (int i = 0; i < 4; ++i) {
    #pragma unroll
    for (int j = 0; j < 4; ++j) {
      int col = colbase + wc + j*16 + dcol;
      #pragma unroll
      for (int r = 0; r < 4; ++r) {
        int row = rowbase + wr + i*16 + drow4 + r;
        wb[(size_t)row * 512 + col] = f2b(acc[i][j][r]);
      }
    }
  }
}

// One block per node (n = nb0 + blockIdx.x). wb is CSR-local for this half.
// AGG[n][m][c] = (1/16) * sum_e w[slot(e)][c*4+l(m)] * h0[send_e][c] * sh[e][m]
constexpr int CH = 16;
__global__ __launch_bounds__(512) void gather_kernel(
    const int* __restrict__ offs, const int* __restrict__ eids,
    const int* __restrict__ ei, int nb0,
    const ushort_t* __restrict__ wb,
    const float* __restrict__ sh,
    const ushort_t* __restrict__ H,
    ushort_t* __restrict__ AGG)
{
  __shared__ ushort_t ws[CH][512];
  __shared__ ushort_t h0s[CH][128];
  __shared__ float shs[CH][16];
  int n = nb0 + blockIdx.x;
  int t = threadIdx.x;
  int l = t >> 7;       // wave-uniform
  int c = t & 127;
  const int wstart = offs[nb0];
  float a0=0,a1=0,a2=0,a3=0,a4=0,a5=0,a6=0;
  const int e0 = offs[n], e1 = offs[n+1];
  for (int base = e0; base < e1; base += CH) {
    const int cnt = min(CH, e1 - base);
    // stage w: contiguous CSR rows, CH*512 bf16 = 1024 int4, 2 per thread
    #pragma unroll
    for (int rep = 0; rep < 2; ++rep) {
      int idx = rep * 512 + t;
      int j = idx >> 6, seg = idx & 63;
      if (j < cnt)
        *(int4*)&ws[j][seg * 8] = *(const int4*)&wb[(size_t)(base - wstart + j) * 512 + seg * 8];
    }
    // stage h0 (bf16) and sh (f32)
    if (t < 256) {
      int j = t >> 4, seg = t & 15;
      if (j < cnt) {
        int e = eids[base + j];
        *(int4*)&h0s[j][seg * 8] = *(const int4*)&H[(size_t)ei[e] * 2048 + seg * 8];
      }
    } else if (t < 320) {
      int tt = t - 256, j = tt >> 2, seg = tt & 3;
      if (j < cnt)
        *(float4*)&shs[j][seg * 4] = *(const float4*)&sh[(size_t)eids[base + j] * 16 + seg * 4];
    }
    __syncthreads();
    for (int j = 0; j < cnt; ++j) {
      float wv = b2f(ws[j][(c << 2) | l]);
      float wh = wv * b2f(h0s[j][c]);
      if (l == 0) {
        a0 = fmaf(wh, shs[j][0], a0);
      } else if (l == 1) {
        float4 s4 = *(const float4*)&shs[j][0];
        a0 = fmaf(wh, s4.y, a0); a1 = fmaf(wh, s4.z, a1); a2 = fmaf(wh, s4.w, a2);
      } else if (l == 2) {
        float4 s4 = *(const float4*)&shs[j][4];
        float s8 = shs[j][8];
        a0 = fmaf(wh, s4.x, a0); a1 = fmaf(wh, s4.y, a1); a2 = fmaf(wh, s4.z, a2);
        a3 = fmaf(wh, s4.w, a3); a4 = fmaf(wh, s8, a4);
      } else {
        float4 sA = *(const float4*)&shs[j][8];
        float4 sB = *(const float4*)&shs[j][12];
        a0 = fmaf(wh, sA.y, a0); a1 = fmaf(wh, sA.z, a1); a2 = fmaf(wh, sA.w, a2);
        a3 = fmaf(wh, sB.x, a3); a4 = fmaf(wh, sB.y, a4); a5 = fmaf(wh, sB.z, a5);
        a6 = fmaf(wh, sB.w, a6);
      }
    }
    __syncthreads();
  }
  const float inv16 = 0.0625f;
  size_t baseo = (size_t)n * 2048 + c;
  if (l == 0) {
    AGG[baseo] = f2b(a0 * inv16);
  } else if (l == 1) {
    AGG[baseo + 1*128] = f2b(a0*inv16); AGG[baseo + 2*128] = f2b(a1*inv16); AGG[baseo + 3*128] = f2b(a2*inv16);
  } else if (l == 2) {
    AGG[baseo + 4*128] = f2b(a0*inv16); AGG[baseo + 5*128] = f2b(a1*inv16); AGG[baseo + 6*128] = f2b(a2*inv16);
    AGG[baseo + 7*128] = f2b(a3*inv16); AGG[baseo + 8*128] = f2b(a4*inv16);
  } else {
    AGG[baseo + 9*128]  = f2b(a0*inv16); AGG[baseo + 10*128] = f2b(a1*inv16); AGG[baseo + 11*128] = f2b(a2*inv16);
    AGG[baseo + 12*128] = f2b(a3*inv16); AGG[baseo + 13*128] = f2b(a4*inv16); AGG[baseo + 14*128] = f2b(a5*inv16);
    AGG[baseo + 15*128] = f2b(a6*inv16);
  }
}

__global__ __launch_bounds__(256) void scale_kernel(const ushort_t* __restrict__ M,
                                                    const int* __restrict__ elem,
                                                    const float* __restrict__ wprodL,
                                                    float* __restrict__ scale) {
  int i = blockIdx.x * 256 + threadIdx.x;  // n*128 + c
  int n = i >> 7, c = i & 127;
  float s = b2f(M[(size_t)n * 2048 + c]);
  const float* co = wprodL + ((size_t)elem[n] * 128 + c) * 3;
  scale[i] = co[0] + s * (co[1] + s * co[2]);
}

__global__ __launch_bounds__(64) void readout_kernel(const ushort_t* __restrict__ F,
                                                     const float* __restrict__ ro0,
                                                     const float* __restrict__ ro1,
                                                     const float* __restrict__ ro2,
                                                     float* __restrict__ out, int layer) {
  int n = blockIdx.x; int t = threadIdx.x;
  const ushort_t* fr = F + (size_t)n * 2048;   // feats[n][0][:]
  float f0 = b2f(fr[t]), f1 = b2f(fr[t + 64]);
  if (layer == 0) {
    float v = f0 * ro0[t] + f1 * ro0[t + 64];
    #pragma unroll
    for (int m = 32; m > 0; m >>= 1) v += __shfl_xor(v, m, 64);
    if (t == 0) out[n] = v;
  } else {
    float acc = 0.f;
    for (int h = 0; h < 16; ++h) {
      float p = f0 * ro1[t*16 + h] + f1 * ro1[(t + 64)*16 + h];
      #pragma unroll
      for (int m = 32; m > 0; m >>= 1) p += __shfl_xor(p, m, 64);
      acc = fmaf(silu_f(p), ro2[h], acc);
    }
    if (t == 0) out[n] += acc;
  }
}

extern "C" void kernel_launch(void* const* d_in, const int* in_sizes, int n_in,
                              void* d_out, int out_size, void* d_ws, size_t ws_size,
                              hipStream_t stream) {
  (void)in_sizes; (void)n_in; (void)out_size;
  const float* positions = (const float*)d_in[0];
  const float* node_attrs= (const float*)d_in[1];
  const float* shifts    = (const float*)d_in[2];
  const float* W_embed   = (const float*)d_in[3];
  const float* W_up      = (const float*)d_in[4];
  const float* R_w1      = (const float*)d_in[5];
  const float* R_w2      = (const float*)d_in[6];
  const float* R_w3      = (const float*)d_in[7];
  const float* W_out     = (const float*)d_in[8];
  const float* w_sc      = (const float*)d_in[9];
  const float* w_prod    = (const float*)d_in[10];
  const float* W_plin    = (const float*)d_in[11];
  const float* w_ro0     = (const float*)d_in[12];
  const float* ro_w1     = (const float*)d_in[13];
  const float* ro_w2     = (const float*)d_in[14];
  const int*   ei        = (const int*)d_in[15];
  float* out = (float*)d_out;

  char* ws_ptr = (char*)d_ws;
  size_t off = 0;
  auto alloc = [&](size_t nbytes) -> void* {
    void* p = ws_ptr + off;
    off += (nbytes + 255) & ~(size_t)255;
    return p;
  };
  const size_t PB = (size_t)kN * 16 * 128 * sizeof(ushort_t);  // 33.5 MB
  ushort_t* P0   = (ushort_t*)alloc(PB);
  ushort_t* P1   = (ushort_t*)alloc(PB);
  ushort_t* P2   = (ushort_t*)alloc(PB);
  float* shb     = (float*)alloc((size_t)kE * 16 * 4);          // 8.4 MB
  float* rbb     = (float*)alloc((size_t)kE * 8 * 4);           // 4.2 MB
  ushort_t* r2b  = (ushort_t*)alloc((size_t)kE * 64 * 2);       // 16.8 MB
  float* scaleb  = (float*)alloc((size_t)kN * 128 * 4);         // 4.2 MB
  ushort_t* wb   = (ushort_t*)alloc((size_t)kWbRows * 512 * 2); // 71.3 MB
  ushort_t* R3T0 = (ushort_t*)alloc(512 * 64 * 2);
  ushort_t* R3T1 = (ushort_t*)alloc(512 * 64 * 2);
  ushort_t* WTu0 = (ushort_t*)alloc(128 * 128 * 2);
  ushort_t* WTu1 = (ushort_t*)alloc(128 * 128 * 2);
  ushort_t* WTo0 = (ushort_t*)alloc(128 * 128 * 2);
  ushort_t* WTo1 = (ushort_t*)alloc(128 * 128 * 2);
  ushort_t* WTp0 = (ushort_t*)alloc(128 * 128 * 2);
  ushort_t* WTp1 = (ushort_t*)alloc(128 * 128 * 2);
  int* elemb  = (int*)alloc(kN * 4);
  int* counts = (int*)alloc(kN * 4);
  int* cursor = (int*)alloc(kN * 4);
  int* offsb  = (int*)alloc((kN + 1) * 4);
  int* eidsb  = (int*)alloc((size_t)kE * 4);
  if (off > ws_size) return;  // total ~206.5 MB (known-good 252.5 MB fit previously)

  // ---- prep ----
  zero_ints_kernel<<<kN/256, 256, 0, stream>>>(counts, cursor);
  elem_kernel<<<kN/256, 256, 0, stream>>>(node_attrs, elemb);
  init_feats_kernel<<<(kN*128)/256, 256, 0, stream>>>(W_embed, elemb, P0);
  geom_kernel<<<kE/256, 256, 0, stream>>>(positions, shifts, ei, shb, rbb);
  count_kernel<<<kE/256, 256, 0, stream>>>(ei, counts);
  scan_kernel<<<1, 1024, 0, stream>>>(counts, offsb);
  fill_kernel<<<kE/256, 256, 0, stream>>>(ei, offsb, cursor, eidsb);
  transpose_w_kernel<<<64, 256, 0, stream>>>(W_up, WTu0);
  transpose_w_kernel<<<64, 256, 0, stream>>>(W_up + 16384, WTu1);
  transpose_w_kernel<<<64, 256, 0, stream>>>(W_out, WTo0);
  transpose_w_kernel<<<64, 256, 0, stream>>>(W_out + 16384, WTo1);
  transpose_w_kernel<<<64, 256, 0, stream>>>(W_plin, WTp0);
  transpose_w_kernel<<<64, 256, 0, stream>>>(W_plin + 16384, WTp1);
  transpose_r3_kernel<<<128, 256, 0, stream>>>(R_w3, R3T0);
  transpose_r3_kernel<<<128, 256, 0, stream>>>(R_w3 + 32768, R3T1);

  // ---- layer 0 (feats nonzero only at m=0) ----
  radial_kernel<<<kE/4, 256, 0, stream>>>(rbb, R_w1, R_w2, r2b);
  mgemm_kernel<false,false,false><<<kN/128, 256, 0, stream>>>(
      P0, 2048, WTu0, P1, 2048, nullptr, nullptr, nullptr, nullptr);
  wgemm_kernel<<<dim3(kWbTiles,4), 256, 0, stream>>>(r2b, eidsb, offsb, 0, R3T0, wb);
  gather_kernel<<<kHalfN, 512, 0, stream>>>(offsb, eidsb, ei, 0, wb, shb, P1, P2);
  wgemm_kernel<<<dim3(kWbTiles,4), 256, 0, stream>>>(r2b, eidsb, offsb, kHalfN, R3T0, wb);
  gather_kernel<<<kHalfN, 512, 0, stream>>>(offsb, eidsb, ei, kHalfN, wb, shb, P1, P2);
  mgemm_kernel<false,false,false><<<(kN*16)/128, 256, 0, stream>>>(
      P2, 128, WTo0, P0, 128, nullptr, nullptr, nullptr, nullptr);
  scale_kernel<<<(kN*128)/256, 256, 0, stream>>>(P0, elemb, w_prod, scaleb);
  mgemm_kernel<true,true,true><<<(kN*16)/128, 256, 0, stream>>>(
      P0, 128, WTp0, P2, 128, scaleb, P1, w_sc, elemb);
  readout_kernel<<<kN, 64, 0, stream>>>(P2, w_ro0, ro_w1, ro_w2, out, 0);

  // ---- layer 1 ----
  radial_kernel<<<kE/4, 256, 0, stream>>>(rbb, R_w1 + 512, R_w2 + 4096, r2b);
  mgemm_kernel<false,false,false><<<(kN*16)/128, 256, 0, stream>>>(
      P2, 128, WTu1, P1, 128, nullptr, nullptr, nullptr, nullptr);
  wgemm_kernel<<<dim3(kWbTiles,4), 256, 0, stream>>>(r2b, eidsb, offsb, 0, R3T1, wb);
  gather_kernel<<<kHalfN, 512, 0, stream>>>(offsb, eidsb, ei, 0, wb, shb, P1, P0);
  wgemm_kernel<<<dim3(kWbTiles,4), 256, 0, stream>>>(r2b, eidsb, offsb, kHalfN, R3T1, wb);
  gather_kernel<<<kHalfN, 512, 0, stream>>>(offsb, eidsb, ei, kHalfN, wb, shb, P1, P0);
  mgemm_kernel<false,false,false><<<(kN*16)/128, 256, 0, stream>>>(
      P0, 128, WTo1, P2, 128, nullptr, nullptr, nullptr, nullptr);
  scale_kernel<<<(kN*128)/256, 256, 0, stream>>>(P2, elemb, w_prod + 3840, scaleb);
  mgemm_kernel<true,true,false><<<(kN*16)/128, 256, 0, stream>>>(
      P2, 128, WTp1, P0, 128, scaleb, P1, w_sc + 1280, elemb);
  readout_kernel<<<kN, 64, 0, stream>>>(P0, w_ro0, ro_w1, ro_w2, out, 1);
}

// Round 6
// 547.997 us; speedup vs baseline: 2.5794x; 1.0584x over previous
//
#include <hip/hip_runtime.h>
#include <math.h>

constexpr int kN = 8192;
constexpr int kE = 131072;
constexpr int kHalfN = 4096;
constexpr int kWbTiles = 544;                 // 544*128 = 69632 rows >= half-span (~65536)
constexpr int kWbRows  = kWbTiles * 128;

typedef short bf16x8 __attribute__((ext_vector_type(8)));
typedef float f32x4 __attribute__((ext_vector_type(4)));
typedef unsigned short ushort_t;
typedef unsigned int uint_t;

__device__ __forceinline__ float silu_f(float x) { return x / (1.f + __expf(-x)); }

__device__ __forceinline__ ushort_t f2b(float f) {
  uint_t x = __float_as_uint(f);
  uint_t r = (x + 0x7fffu + ((x >> 16) & 1u)) >> 16;
  return (ushort_t)r;
}
__device__ __forceinline__ float b2f(ushort_t u) {
  return __uint_as_float(((uint_t)u) << 16);
}

__global__ __launch_bounds__(256) void zero_ints_kernel(int* __restrict__ a, int* __restrict__ b) {
  int i = blockIdx.x * 256 + threadIdx.x;
  if (i < kN) { a[i] = 0; b[i] = 0; }
}

__global__ __launch_bounds__(256) void elem_kernel(const float* __restrict__ attrs, int* __restrict__ elem) {
  int n = blockIdx.x * 256 + threadIdx.x;
  if (n >= kN) return;
  const float* a = attrs + (size_t)n * 10;
  int best = 0; float bv = a[0];
  #pragma unroll
  for (int z = 1; z < 10; ++z) { float v = a[z]; if (v > bv) { bv = v; best = z; } }
  elem[n] = best;
}

__global__ __launch_bounds__(256) void init_feats_kernel(const float* __restrict__ W_embed,
                                                         const int* __restrict__ elem,
                                                         ushort_t* __restrict__ F) {
  int i = blockIdx.x * 256 + threadIdx.x;   // n*128 + c
  int n = i >> 7, c = i & 127;
  F[(size_t)n * 2048 + c] = f2b(W_embed[(size_t)elem[n] * 128 + c]);
}

__global__ __launch_bounds__(256) void geom_kernel(const float* __restrict__ pos,
                                                   const float* __restrict__ shifts,
                                                   const int* __restrict__ ei,
                                                   float* __restrict__ sh,
                                                   float* __restrict__ rb) {
  int e = blockIdx.x * 256 + threadIdx.x;
  if (e >= kE) return;
  int s = ei[e], r = ei[kE + e];
  float vx = pos[r*3+0] - pos[s*3+0] + shifts[(size_t)e*3+0];
  float vy = pos[r*3+1] - pos[s*3+1] + shifts[(size_t)e*3+1];
  float vz = pos[r*3+2] - pos[s*3+2] + shifts[(size_t)e*3+2];
  float len = sqrtf(vx*vx + vy*vy + vz*vz) + 1e-9f;
  float inv = 1.f / len;
  float x = vx*inv, y = vy*inv, z = vz*inv;
  float x2 = x*x, y2 = y*y, z2 = z*z;
  const float s3  = 1.7320508075688772f;
  const float s5  = 2.2360679774997896f;
  const float s15 = 3.8729833462074170f;
  const float a33 = 2.0916500663351889f;
  const float a32 = 10.246950765959598f;
  const float a31 = 1.6201851746019651f;
  const float a30 = 1.3228756555322954f;
  float4* shp = (float4*)(sh + (size_t)e * 16);
  shp[0] = make_float4(1.f, s3*x, s3*y, s3*z);
  shp[1] = make_float4(s15*x*y, s15*y*z, 0.5f*s5*(3.f*z2 - 1.f), s15*x*z);
  shp[2] = make_float4(0.5f*s15*(x2 - y2), a33*y*(3.f*x2 - y2), a32*x*y*z, a31*y*(5.f*z2 - 1.f));
  shp[3] = make_float4(a30*z*(5.f*z2 - 3.f), a31*x*(5.f*z2 - 1.f), 0.5f*a32*z*(x2 - y2), a33*x*(x2 - 3.f*y2));
  float xr = len * 0.2f;
  float cut = 0.f;
  if (xr < 1.f) {
    float x5 = xr*xr*xr*xr*xr;
    cut = 1.f - 21.f*x5 + 35.f*x5*xr - 15.f*x5*xr*xr;
  }
  float pref = 0.63245553203367587f * cut * inv;
  const float PI = 3.14159265358979323846f;
  float b[8];
  #pragma unroll
  for (int k = 0; k < 8; ++k) b[k] = pref * sinf((float)(k+1) * PI * xr);
  float4* rbp = (float4*)(rb + (size_t)e * 8);
  rbp[0] = make_float4(b[0], b[1], b[2], b[3]);
  rbp[1] = make_float4(b[4], b[5], b[6], b[7]);
}

__global__ __launch_bounds__(256) void count_kernel(const int* __restrict__ ei, int* __restrict__ counts) {
  int e = blockIdx.x * 256 + threadIdx.x;
  if (e < kE) atomicAdd(&counts[ei[kE + e]], 1);
}

__global__ __launch_bounds__(1024) void scan_kernel(const int* __restrict__ counts, int* __restrict__ offs) {
  __shared__ int tmp[1024];
  int t = threadIdx.x;
  int loc[8]; int s = 0;
  #pragma unroll
  for (int i = 0; i < 8; ++i) { loc[i] = s; s += counts[t*8 + i]; }
  tmp[t] = s;
  __syncthreads();
  for (int d = 1; d < 1024; d <<= 1) {
    int v = (t >= d) ? tmp[t - d] : 0;
    __syncthreads();
    tmp[t] += v;
    __syncthreads();
  }
  int pre = (t == 0) ? 0 : tmp[t - 1];
  #pragma unroll
  for (int i = 0; i < 8; ++i) offs[t*8 + i] = pre + loc[i];
  if (t == 1023) offs[kN] = tmp[1023];
}

__global__ __launch_bounds__(256) void fill_kernel(const int* __restrict__ ei, const int* __restrict__ offs,
                                                   int* __restrict__ cursor, int* __restrict__ eids) {
  int e = blockIdx.x * 256 + threadIdx.x;
  if (e >= kE) return;
  int r = ei[kE + e];
  int pos = atomicAdd(&cursor[r], 1);
  eids[offs[r] + pos] = e;
}

// 32 edges per block: stage W1/W2 once, process 8 groups of 4 edges.
constexpr int kEB = 32;
__global__ __launch_bounds__(256) void radial_kernel(const float* __restrict__ rb,
                                                     const float* __restrict__ W1,
                                                     const float* __restrict__ W2,
                                                     ushort_t* __restrict__ r2) {
  __shared__ float W1s[8*64];
  __shared__ float W2s[64*64];
  __shared__ float r1s[2][4][64];
  int tid = threadIdx.x;
  for (int i = tid; i < 512; i += 256) W1s[i] = W1[i];
  for (int i = tid; i < 4096; i += 256) W2s[i] = W2[i];
  int g = tid >> 6, j = tid & 63;
  __syncthreads();
  #pragma unroll
  for (int cch = 0; cch < kEB/4; ++cch) {
    int e = blockIdx.x * kEB + cch * 4 + g;
    const float* rbe = rb + (size_t)e * 8;
    float v = 0.f;
    #pragma unroll
    for (int i = 0; i < 8; ++i) v = fmaf(rbe[i], W1s[i*64 + j], v);
    r1s[cch & 1][g][j] = silu_f(v);
    __syncthreads();
    float u = 0.f;
    #pragma unroll
    for (int i = 0; i < 64; ++i) u = fmaf(r1s[cch & 1][g][i], W2s[i*64 + j], u);
    r2[(size_t)e * 64 + j] = f2b(silu_f(u));
    // no trailing barrier: next iteration writes the other r1s buffer
  }
}

// WT[d][c] = W[c][d], bf16.  (128x128)
__global__ __launch_bounds__(256) void transpose_w_kernel(const float* __restrict__ W, ushort_t* __restrict__ WT) {
  int i = blockIdx.x * 256 + threadIdx.x;   // d*128 + c
  int d = i >> 7, c = i & 127;
  WT[i] = f2b(W[c*128 + d]);
}

// R3T[t][j] = R_w3[j][t], bf16.  t = c*4+l in [0,512), j in [0,64)
__global__ __launch_bounds__(256) void transpose_r3_kernel(const float* __restrict__ R3, ushort_t* __restrict__ R3T) {
  int i = blockIdx.x * 256 + threadIdx.x;   // t*64 + j
  int t = i >> 6, j = i & 63;
  R3T[i] = f2b(R3[j*512 + t]);
}

// MFMA GEMM (K=128): O[row, col] = sum_k A[row,k] * BT[col,k].
// SCALED: A(row,k) *= scaleBuf[(row>>4)*128 + k].
// EPI: O += H[row*128+col]*wscL[elem[row>>4]*128+col]; L0 limits EPI to row%16==0.
template<bool SCALED, bool EPI, bool L0>
__global__ __launch_bounds__(256) void mgemm_kernel(
    const ushort_t* __restrict__ A, size_t aStride,
    const ushort_t* __restrict__ BT,
    ushort_t* __restrict__ O, size_t oStride,
    const float* __restrict__ scaleBuf,
    const ushort_t* __restrict__ Hbuf,
    const float* __restrict__ wscL,
    const int* __restrict__ elem)
{
  __shared__ ushort_t As[128][136];
  __shared__ ushort_t Bs[128][136];
  const int tid = threadIdx.x;
  const size_t rowbase = (size_t)blockIdx.x * 128;

  for (int idx = tid * 8; idx < 128 * 128; idx += 256 * 8) {
    int r = idx >> 7, k = idx & 127;
    *(int4*)&Bs[r][k] = *(const int4*)&BT[(size_t)r * 128 + k];
  }
  for (int idx = tid * 8; idx < 128 * 128; idx += 256 * 8) {
    int r = idx >> 7, k = idx & 127;
    size_t grow = rowbase + r;
    const ushort_t* ap = A + grow * aStride + k;
    if (SCALED) {
      const float* sp = scaleBuf + (grow >> 4) * 128 + k;
      uint_t u[4];
      #pragma unroll
      for (int q = 0; q < 4; ++q) {
        ushort_t lo = f2b(b2f(ap[2*q])   * sp[2*q]);
        ushort_t hi = f2b(b2f(ap[2*q+1]) * sp[2*q+1]);
        u[q] = (uint_t)lo | ((uint_t)hi << 16);
      }
      *(int4*)&As[r][k] = make_int4((int)u[0], (int)u[1], (int)u[2], (int)u[3]);
    } else {
      *(int4*)&As[r][k] = *(const int4*)ap;
    }
  }
  __syncthreads();

  const int lane = tid & 63, wv = tid >> 6;
  const int wr = (wv >> 1) * 64, wc = (wv & 1) * 64;
  const int fr = lane & 15;
  const int kg = (lane >> 4) * 8;
  f32x4 acc[4][4] = {};
  #pragma unroll
  for (int ks = 0; ks < 4; ++ks) {
    const int k0 = ks * 32 + kg;
    bf16x8 af[4], bfr[4];
    #pragma unroll
    for (int i = 0; i < 4; ++i) af[i]  = *(const bf16x8*)&As[wr + i*16 + fr][k0];
    #pragma unroll
    for (int j = 0; j < 4; ++j) bfr[j] = *(const bf16x8*)&Bs[wc + j*16 + fr][k0];
    #pragma unroll
    for (int i = 0; i < 4; ++i)
      #pragma unroll
      for (int j = 0; j < 4; ++j)
        acc[i][j] = __builtin_amdgcn_mfma_f32_16x16x32_bf16(af[i], bfr[j], acc[i][j], 0, 0, 0);
  }

  const int dcol = lane & 15, drow4 = (lane >> 4) * 4;
  #pragma unroll
  for (int i = 0; i < 4; ++i) {
    #pragma unroll
    for (int j = 0; j < 4; ++j) {
      int col = wc + j*16 + dcol;
      #pragma unroll
      for (int r = 0; r < 4; ++r) {
        int row = wr + i*16 + drow4 + r;
        size_t grow = rowbase + row;
        float v = acc[i][j][r];
        if (EPI) {
          if (!L0 || ((grow & 15) == 0)) {
            int ee = elem[grow >> 4];
            v += b2f(Hbuf[grow * 128 + col]) * wscL[(size_t)ee * 128 + col];
          }
        }
        O[grow * oStride + col] = f2b(v);
      }
    }
  }
}

// w-GEMM, CSR-ordered: wb[local_row][t] = sum_k r2[eids[halfStart+local_row]][k] * R3T[t][k]
__global__ __launch_bounds__(256) void wgemm_kernel(
    const ushort_t* __restrict__ r2, const int* __restrict__ eids,
    const int* __restrict__ offs, int nb0,
    const ushort_t* __restrict__ R3T, ushort_t* __restrict__ wb)
{
  __shared__ ushort_t As[128][72];
  __shared__ ushort_t Bs[128][72];
  const int tid = threadIdx.x;
  const int rowbase = blockIdx.x * 128;
  const int colbase = blockIdx.y * 128;
  const int halfStart = offs[nb0];
  const int halfEnd   = offs[nb0 + kHalfN];

  for (int idx = tid * 8; idx < 128 * 64; idx += 256 * 8) {
    int r = idx >> 6, k = idx & 63;
    *(int4*)&Bs[r][k] = *(const int4*)&R3T[(size_t)(colbase + r) * 64 + k];
  }
  for (int idx = tid * 8; idx < 128 * 64; idx += 256 * 8) {
    int r = idx >> 6, k = idx & 63;
    int ii = halfStart + rowbase + r;
    int iic = ii < halfEnd ? ii : (halfEnd - 1);
    if (iic < 0) iic = 0;
    int e = eids[iic];
    *(int4*)&As[r][k] = *(const int4*)&r2[(size_t)e * 64 + k];
  }
  __syncthreads();

  const int lane = tid & 63, wv = tid >> 6;
  const int wr = (wv >> 1) * 64, wc = (wv & 1) * 64;
  const int fr = lane & 15;
  const int kg = (lane >> 4) * 8;
  f32x4 acc[4][4] = {};
  #pragma unroll
  for (int ks = 0; ks < 2; ++ks) {
    const int k0 = ks * 32 + kg;
    bf16x8 af[4], bfr[4];
    #pragma unroll
    for (int i = 0; i < 4; ++i) af[i]  = *(const bf16x8*)&As[wr + i*16 + fr][k0];
    #pragma unroll
    for (int j = 0; j < 4; ++j) bfr[j] = *(const bf16x8*)&Bs[wc + j*16 + fr][k0];
    #pragma unroll
    for (int i = 0; i < 4; ++i)
      #pragma unroll
      for (int j = 0; j < 4; ++j)
        acc[i][j] = __builtin_amdgcn_mfma_f32_16x16x32_bf16(af[i], bfr[j], acc[i][j], 0, 0, 0);
  }

  const int dcol = lane & 15, drow4 = (lane >> 4) * 4;
  #pragma unroll
  for (int i = 0; i < 4; ++i) {
    #pragma unroll
    for (int j = 0; j < 4; ++j) {
      int col = colbase + wc + j*16 + dcol;
      #pragma unroll
      for (int r = 0; r < 4; ++r) {
        int row = rowbase + wr + i*16 + drow4 + r;
        wb[(size_t)row * 512 + col] = f2b(acc[i][j][r]);
      }
    }
  }
}

// One block per node (n = nb0 + blockIdx.x). wb is CSR-local for this half.
constexpr int CH = 16;
__global__ __launch_bounds__(512) void gather_kernel(
    const int* __restrict__ offs, const int* __restrict__ eids,
    const int* __restrict__ ei, int nb0,
    const ushort_t* __restrict__ wb,
    const float* __restrict__ sh,
    const ushort_t* __restrict__ H,
    ushort_t* __restrict__ AGG)
{
  __shared__ ushort_t ws[CH][512];
  __shared__ ushort_t h0s[CH][128];
  __shared__ float shs[CH][16];
  int n = nb0 + blockIdx.x;
  int t = threadIdx.x;
  int l = t >> 7;       // wave-uniform
  int c = t & 127;
  const int wstart = offs[nb0];
  float a0=0,a1=0,a2=0,a3=0,a4=0,a5=0,a6=0;
  const int e0 = offs[n], e1 = offs[n+1];
  for (int base = e0; base < e1; base += CH) {
    const int cnt = min(CH, e1 - base);
    #pragma unroll
    for (int rep = 0; rep < 2; ++rep) {
      int idx = rep * 512 + t;
      int j = idx >> 6, seg = idx & 63;
      if (j < cnt)
        *(int4*)&ws[j][seg * 8] = *(const int4*)&wb[(size_t)(base - wstart + j) * 512 + seg * 8];
    }
    if (t < 256) {
      int j = t >> 4, seg = t & 15;
      if (j < cnt) {
        int e = eids[base + j];
        *(int4*)&h0s[j][seg * 8] = *(const int4*)&H[(size_t)ei[e] * 2048 + seg * 8];
      }
    } else if (t < 320) {
      int tt = t - 256, j = tt >> 2, seg = tt & 3;
      if (j < cnt)
        *(float4*)&shs[j][seg * 4] = *(const float4*)&sh[(size_t)eids[base + j] * 16 + seg * 4];
    }
    __syncthreads();
    for (int j = 0; j < cnt; ++j) {
      float wv = b2f(ws[j][(c << 2) | l]);
      float wh = wv * b2f(h0s[j][c]);
      if (l == 0) {
        a0 = fmaf(wh, shs[j][0], a0);
      } else if (l == 1) {
        float4 s4 = *(const float4*)&shs[j][0];
        a0 = fmaf(wh, s4.y, a0); a1 = fmaf(wh, s4.z, a1); a2 = fmaf(wh, s4.w, a2);
      } else if (l == 2) {
        float4 s4 = *(const float4*)&shs[j][4];
        float s8 = shs[j][8];
        a0 = fmaf(wh, s4.x, a0); a1 = fmaf(wh, s4.y, a1); a2 = fmaf(wh, s4.z, a2);
        a3 = fmaf(wh, s4.w, a3); a4 = fmaf(wh, s8, a4);
      } else {
        float4 sA = *(const float4*)&shs[j][8];
        float4 sB = *(const float4*)&shs[j][12];
        a0 = fmaf(wh, sA.y, a0); a1 = fmaf(wh, sA.z, a1); a2 = fmaf(wh, sA.w, a2);
        a3 = fmaf(wh, sB.x, a3); a4 = fmaf(wh, sB.y, a4); a5 = fmaf(wh, sB.z, a5);
        a6 = fmaf(wh, sB.w, a6);
      }
    }
    __syncthreads();
  }
  const float inv16 = 0.0625f;
  size_t baseo = (size_t)n * 2048 + c;
  if (l == 0) {
    AGG[baseo] = f2b(a0 * inv16);
  } else if (l == 1) {
    AGG[baseo + 1*128] = f2b(a0*inv16); AGG[baseo + 2*128] = f2b(a1*inv16); AGG[baseo + 3*128] = f2b(a2*inv16);
  } else if (l == 2) {
    AGG[baseo + 4*128] = f2b(a0*inv16); AGG[baseo + 5*128] = f2b(a1*inv16); AGG[baseo + 6*128] = f2b(a2*inv16);
    AGG[baseo + 7*128] = f2b(a3*inv16); AGG[baseo + 8*128] = f2b(a4*inv16);
  } else {
    AGG[baseo + 9*128]  = f2b(a0*inv16); AGG[baseo + 10*128] = f2b(a1*inv16); AGG[baseo + 11*128] = f2b(a2*inv16);
    AGG[baseo + 12*128] = f2b(a3*inv16); AGG[baseo + 13*128] = f2b(a4*inv16); AGG[baseo + 14*128] = f2b(a5*inv16);
    AGG[baseo + 15*128] = f2b(a6*inv16);
  }
}

__global__ __launch_bounds__(256) void scale_kernel(const ushort_t* __restrict__ M,
                                                    const int* __restrict__ elem,
                                                    const float* __restrict__ wprodL,
                                                    float* __restrict__ scale) {
  int i = blockIdx.x * 256 + threadIdx.x;  // n*128 + c
  int n = i >> 7, c = i & 127;
  float s = b2f(M[(size_t)n * 2048 + c]);
  const float* co = wprodL + ((size_t)elem[n] * 128 + c) * 3;
  scale[i] = co[0] + s * (co[1] + s * co[2]);
}

__global__ __launch_bounds__(64) void readout_kernel(const ushort_t* __restrict__ F,
                                                     const float* __restrict__ ro0,
                                                     const float* __restrict__ ro1,
                                                     const float* __restrict__ ro2,
                                                     float* __restrict__ out, int layer) {
  int n = blockIdx.x; int t = threadIdx.x;
  const ushort_t* fr = F + (size_t)n * 2048;   // feats[n][0][:]
  float f0 = b2f(fr[t]), f1 = b2f(fr[t + 64]);
  if (layer == 0) {
    float v = f0 * ro0[t] + f1 * ro0[t + 64];
    #pragma unroll
    for (int m = 32; m > 0; m >>= 1) v += __shfl_xor(v, m, 64);
    if (t == 0) out[n] = v;
  } else {
    float acc = 0.f;
    for (int h = 0; h < 16; ++h) {
      float p = f0 * ro1[t*16 + h] + f1 * ro1[(t + 64)*16 + h];
      #pragma unroll
      for (int m = 32; m > 0; m >>= 1) p += __shfl_xor(p, m, 64);
      acc = fmaf(silu_f(p), ro2[h], acc);
    }
    if (t == 0) out[n] += acc;
  }
}

extern "C" void kernel_launch(void* const* d_in, const int* in_sizes, int n_in,
                              void* d_out, int out_size, void* d_ws, size_t ws_size,
                              hipStream_t stream) {
  (void)in_sizes; (void)n_in; (void)out_size;
  const float* positions = (const float*)d_in[0];
  const float* node_attrs= (const float*)d_in[1];
  const float* shifts    = (const float*)d_in[2];
  const float* W_embed   = (const float*)d_in[3];
  const float* W_up      = (const float*)d_in[4];
  const float* R_w1      = (const float*)d_in[5];
  const float* R_w2      = (const float*)d_in[6];
  const float* R_w3      = (const float*)d_in[7];
  const float* W_out     = (const float*)d_in[8];
  const float* w_sc      = (const float*)d_in[9];
  const float* w_prod    = (const float*)d_in[10];
  const float* W_plin    = (const float*)d_in[11];
  const float* w_ro0     = (const float*)d_in[12];
  const float* ro_w1     = (const float*)d_in[13];
  const float* ro_w2     = (const float*)d_in[14];
  const int*   ei        = (const int*)d_in[15];
  float* out = (float*)d_out;

  char* ws_ptr = (char*)d_ws;
  size_t off = 0;
  auto alloc = [&](size_t nbytes) -> void* {
    void* p = ws_ptr + off;
    off += (nbytes + 255) & ~(size_t)255;
    return p;
  };
  const size_t PB = (size_t)kN * 16 * 128 * sizeof(ushort_t);  // 33.5 MB
  ushort_t* P0   = (ushort_t*)alloc(PB);
  ushort_t* P1   = (ushort_t*)alloc(PB);
  ushort_t* P2   = (ushort_t*)alloc(PB);
  float* shb     = (float*)alloc((size_t)kE * 16 * 4);          // 8.4 MB
  float* rbb     = (float*)alloc((size_t)kE * 8 * 4);           // 4.2 MB
  ushort_t* r2b  = (ushort_t*)alloc((size_t)kE * 64 * 2);       // 16.8 MB
  float* scaleb  = (float*)alloc((size_t)kN * 128 * 4);         // 4.2 MB
  ushort_t* wb   = (ushort_t*)alloc((size_t)kWbRows * 512 * 2); // 71.3 MB
  ushort_t* R3T0 = (ushort_t*)alloc(512 * 64 * 2);
  ushort_t* R3T1 = (ushort_t*)alloc(512 * 64 * 2);
  ushort_t* WTu0 = (ushort_t*)alloc(128 * 128 * 2);
  ushort_t* WTu1 = (ushort_t*)alloc(128 * 128 * 2);
  ushort_t* WTo0 = (ushort_t*)alloc(128 * 128 * 2);
  ushort_t* WTo1 = (ushort_t*)alloc(128 * 128 * 2);
  ushort_t* WTp0 = (ushort_t*)alloc(128 * 128 * 2);
  ushort_t* WTp1 = (ushort_t*)alloc(128 * 128 * 2);
  int* elemb  = (int*)alloc(kN * 4);
  int* counts = (int*)alloc(kN * 4);
  int* cursor = (int*)alloc(kN * 4);
  int* offsb  = (int*)alloc((kN + 1) * 4);
  int* eidsb  = (int*)alloc((size_t)kE * 4);
  if (off > ws_size) return;

  // ---- prep ----
  zero_ints_kernel<<<kN/256, 256, 0, stream>>>(counts, cursor);
  elem_kernel<<<kN/256, 256, 0, stream>>>(node_attrs, elemb);
  init_feats_kernel<<<(kN*128)/256, 256, 0, stream>>>(W_embed, elemb, P0);
  geom_kernel<<<kE/256, 256, 0, stream>>>(positions, shifts, ei, shb, rbb);
  count_kernel<<<kE/256, 256, 0, stream>>>(ei, counts);
  scan_kernel<<<1, 1024, 0, stream>>>(counts, offsb);
  fill_kernel<<<kE/256, 256, 0, stream>>>(ei, offsb, cursor, eidsb);
  transpose_w_kernel<<<64, 256, 0, stream>>>(W_up, WTu0);
  transpose_w_kernel<<<64, 256, 0, stream>>>(W_up + 16384, WTu1);
  transpose_w_kernel<<<64, 256, 0, stream>>>(W_out, WTo0);
  transpose_w_kernel<<<64, 256, 0, stream>>>(W_out + 16384, WTo1);
  transpose_w_kernel<<<64, 256, 0, stream>>>(W_plin, WTp0);
  transpose_w_kernel<<<64, 256, 0, stream>>>(W_plin + 16384, WTp1);
  transpose_r3_kernel<<<128, 256, 0, stream>>>(R_w3, R3T0);
  transpose_r3_kernel<<<128, 256, 0, stream>>>(R_w3 + 32768, R3T1);

  // ---- layer 0 (feats nonzero only at m=0) ----
  radial_kernel<<<kE/kEB, 256, 0, stream>>>(rbb, R_w1, R_w2, r2b);
  mgemm_kernel<false,false,false><<<kN/128, 256, 0, stream>>>(
      P0, 2048, WTu0, P1, 2048, nullptr, nullptr, nullptr, nullptr);
  wgemm_kernel<<<dim3(kWbTiles,4), 256, 0, stream>>>(r2b, eidsb, offsb, 0, R3T0, wb);
  gather_kernel<<<kHalfN, 512, 0, stream>>>(offsb, eidsb, ei, 0, wb, shb, P1, P2);
  wgemm_kernel<<<dim3(kWbTiles,4), 256, 0, stream>>>(r2b, eidsb, offsb, kHalfN, R3T0, wb);
  gather_kernel<<<kHalfN, 512, 0, stream>>>(offsb, eidsb, ei, kHalfN, wb, shb, P1, P2);
  mgemm_kernel<false,false,false><<<(kN*16)/128, 256, 0, stream>>>(
      P2, 128, WTo0, P0, 128, nullptr, nullptr, nullptr, nullptr);
  scale_kernel<<<(kN*128)/256, 256, 0, stream>>>(P0, elemb, w_prod, scaleb);
  mgemm_kernel<true,true,true><<<(kN*16)/128, 256, 0, stream>>>(
      P0, 128, WTp0, P2, 128, scaleb, P1, w_sc, elemb);
  readout_kernel<<<kN, 64, 0, stream>>>(P2, w_ro0, ro_w1, ro_w2, out, 0);

  // ---- layer 1 ----
  radial_kernel<<<kE/kEB, 256, 0, stream>>>(rbb, R_w1 + 512, R_w2 + 4096, r2b);
  mgemm_kernel<false,false,false><<<(kN*16)/128, 256, 0, stream>>>(
      P2, 128, WTu1, P1, 128, nullptr, nullptr, nullptr, nullptr);
  wgemm_kernel<<<dim3(kWbTiles,4), 256, 0, stream>>>(r2b, eidsb, offsb, 0, R3T1, wb);
  gather_kernel<<<kHalfN, 512, 0, stream>>>(offsb, eidsb, ei, 0, wb, shb, P1, P0);
  wgemm_kernel<<<dim3(kWbTiles,4), 256, 0, stream>>>(r2b, eidsb, offsb, kHalfN, R3T1, wb);
  gather_kernel<<<kHalfN, 512, 0, stream>>>(offsb, eidsb, ei, kHalfN, wb, shb, P1, P0);
  mgemm_kernel<false,false,false><<<(kN*16)/128, 256, 0, stream>>>(
      P0, 128, WTo1, P2, 128, nullptr, nullptr, nullptr, nullptr);
  scale_kernel<<<(kN*128)/256, 256, 0, stream>>>(P2, elemb, w_prod + 3840, scaleb);
  mgemm_kernel<true,true,false><<<(kN*16)/128, 256, 0, stream>>>(
      P2, 128, WTp1, P0, 128, scaleb, P1, w_sc + 1280, elemb);
  readout_kernel<<<kN, 64, 0, stream>>>(P0, w_ro0, ro_w1, ro_w2, out, 1);
}

// Round 7
// 471.140 us; speedup vs baseline: 3.0002x; 1.1631x over previous
//
#include <hip/hip_runtime.h>
#include <math.h>

constexpr int kN = 8192;
constexpr int kE = 131072;
constexpr int kHalfN = 4096;
constexpr int kWbTiles = 544;                 // 544*128 = 69632 rows >= half-span (~65536)
constexpr int kWbRows  = kWbTiles * 128;

typedef short bf16x8 __attribute__((ext_vector_type(8)));
typedef float f32x4 __attribute__((ext_vector_type(4)));
typedef unsigned short ushort_t;
typedef unsigned int uint_t;

__device__ __forceinline__ float silu_f(float x) { return x / (1.f + __expf(-x)); }

__device__ __forceinline__ ushort_t f2b(float f) {
  uint_t x = __float_as_uint(f);
  uint_t r = (x + 0x7fffu + ((x >> 16) & 1u)) >> 16;
  return (ushort_t)r;
}
__device__ __forceinline__ float b2f(ushort_t u) {
  return __uint_as_float(((uint_t)u) << 16);
}

__global__ __launch_bounds__(256) void zero_ints_kernel(int* __restrict__ a, int* __restrict__ b) {
  int i = blockIdx.x * 256 + threadIdx.x;
  if (i < kN) { a[i] = 0; b[i] = 0; }
}

__global__ __launch_bounds__(256) void elem_kernel(const float* __restrict__ attrs, int* __restrict__ elem) {
  int n = blockIdx.x * 256 + threadIdx.x;
  if (n >= kN) return;
  const float* a = attrs + (size_t)n * 10;
  int best = 0; float bv = a[0];
  #pragma unroll
  for (int z = 1; z < 10; ++z) { float v = a[z]; if (v > bv) { bv = v; best = z; } }
  elem[n] = best;
}

__global__ __launch_bounds__(256) void init_feats_kernel(const float* __restrict__ W_embed,
                                                         const int* __restrict__ elem,
                                                         ushort_t* __restrict__ F) {
  int i = blockIdx.x * 256 + threadIdx.x;   // n*128 + c
  int n = i >> 7, c = i & 127;
  F[(size_t)n * 2048 + c] = f2b(W_embed[(size_t)elem[n] * 128 + c]);
}

__global__ __launch_bounds__(256) void geom_kernel(const float* __restrict__ pos,
                                                   const float* __restrict__ shifts,
                                                   const int* __restrict__ ei,
                                                   float* __restrict__ sh,
                                                   float* __restrict__ rb) {
  int e = blockIdx.x * 256 + threadIdx.x;
  if (e >= kE) return;
  int s = ei[e], r = ei[kE + e];
  float vx = pos[r*3+0] - pos[s*3+0] + shifts[(size_t)e*3+0];
  float vy = pos[r*3+1] - pos[s*3+1] + shifts[(size_t)e*3+1];
  float vz = pos[r*3+2] - pos[s*3+2] + shifts[(size_t)e*3+2];
  float len = sqrtf(vx*vx + vy*vy + vz*vz) + 1e-9f;
  float inv = 1.f / len;
  float x = vx*inv, y = vy*inv, z = vz*inv;
  float x2 = x*x, y2 = y*y, z2 = z*z;
  const float s3  = 1.7320508075688772f;
  const float s5  = 2.2360679774997896f;
  const float s15 = 3.8729833462074170f;
  const float a33 = 2.0916500663351889f;
  const float a32 = 10.246950765959598f;
  const float a31 = 1.6201851746019651f;
  const float a30 = 1.3228756555322954f;
  float4* shp = (float4*)(sh + (size_t)e * 16);
  shp[0] = make_float4(1.f, s3*x, s3*y, s3*z);
  shp[1] = make_float4(s15*x*y, s15*y*z, 0.5f*s5*(3.f*z2 - 1.f), s15*x*z);
  shp[2] = make_float4(0.5f*s15*(x2 - y2), a33*y*(3.f*x2 - y2), a32*x*y*z, a31*y*(5.f*z2 - 1.f));
  shp[3] = make_float4(a30*z*(5.f*z2 - 3.f), a31*x*(5.f*z2 - 1.f), 0.5f*a32*z*(x2 - y2), a33*x*(x2 - 3.f*y2));
  float xr = len * 0.2f;
  float cut = 0.f;
  if (xr < 1.f) {
    float x5 = xr*xr*xr*xr*xr;
    cut = 1.f - 21.f*x5 + 35.f*x5*xr - 15.f*x5*xr*xr;
  }
  float pref = 0.63245553203367587f * cut * inv;
  const float PI = 3.14159265358979323846f;
  float theta = PI * xr;
  float sn, cs;
  __sincosf(theta, &sn, &cs);
  float twoc = 2.f * cs;
  float b[8];
  float s_prev = 0.f, s_cur = sn;
  b[0] = pref * s_cur;
  #pragma unroll
  for (int k = 1; k < 8; ++k) {
    float s_next = twoc * s_cur - s_prev;
    s_prev = s_cur; s_cur = s_next;
    b[k] = pref * s_cur;
  }
  float4* rbp = (float4*)(rb + (size_t)e * 8);
  rbp[0] = make_float4(b[0], b[1], b[2], b[3]);
  rbp[1] = make_float4(b[4], b[5], b[6], b[7]);
}

__global__ __launch_bounds__(256) void count_kernel(const int* __restrict__ ei, int* __restrict__ counts) {
  int e = blockIdx.x * 256 + threadIdx.x;
  if (e < kE) atomicAdd(&counts[ei[kE + e]], 1);
}

__global__ __launch_bounds__(1024) void scan_kernel(const int* __restrict__ counts, int* __restrict__ offs) {
  __shared__ int tmp[1024];
  int t = threadIdx.x;
  int loc[8]; int s = 0;
  #pragma unroll
  for (int i = 0; i < 8; ++i) { loc[i] = s; s += counts[t*8 + i]; }
  tmp[t] = s;
  __syncthreads();
  for (int d = 1; d < 1024; d <<= 1) {
    int v = (t >= d) ? tmp[t - d] : 0;
    __syncthreads();
    tmp[t] += v;
    __syncthreads();
  }
  int pre = (t == 0) ? 0 : tmp[t - 1];
  #pragma unroll
  for (int i = 0; i < 8; ++i) offs[t*8 + i] = pre + loc[i];
  if (t == 1023) offs[kN] = tmp[1023];
}

__global__ __launch_bounds__(256) void fill_kernel(const int* __restrict__ ei, const int* __restrict__ offs,
                                                   int* __restrict__ cursor, int* __restrict__ eids) {
  int e = blockIdx.x * 256 + threadIdx.x;
  if (e >= kE) return;
  int r = ei[kE + e];
  int pos = atomicAdd(&cursor[r], 1);
  eids[offs[r] + pos] = e;
}

// Radial MLP, 128 edges/block. Phase 1 (K=8) on f32 VALU; phase 2 (64x64) on MFMA.
__global__ __launch_bounds__(256) void radial_kernel(const float* __restrict__ rb,
                                                     const float* __restrict__ W1,
                                                     const float* __restrict__ W2,
                                                     ushort_t* __restrict__ r2) {
  __shared__ float rbs[128][8];
  __shared__ float W1s[8*64];
  __shared__ ushort_t B2s[64][72];   // B2s[col][k] = W2[k][col], bf16
  __shared__ ushort_t r1s[128][72];  // r1 bf16 (then reused for r2 staging)
  const int tid = threadIdx.x;
  const size_t ebase = (size_t)blockIdx.x * 128;
  {
    int r = tid >> 1, q = tid & 1;
    *(float4*)&rbs[r][q*4] = *(const float4*)&rb[(ebase + r)*8 + q*4];
  }
  for (int i = tid; i < 512; i += 256) W1s[i] = W1[i];
  for (int i = tid; i < 4096; i += 256) {
    int k = i >> 6, col = i & 63;
    B2s[col][k] = f2b(W2[i]);
  }
  __syncthreads();
  // phase 1: r1 = silu(rb @ W1), f32
  {
    int col = tid & 63;
    int r0 = (tid >> 6) * 32;
    #pragma unroll 4
    for (int rr = 0; rr < 32; ++rr) {
      int row = r0 + rr;
      float v = 0.f;
      #pragma unroll
      for (int i = 0; i < 8; ++i) v = fmaf(rbs[row][i], W1s[i*64 + col], v);
      r1s[row][col] = f2b(silu_f(v));
    }
  }
  __syncthreads();
  // phase 2: r2 = silu(r1 @ W2) via MFMA. wave wv: rows wv*32..+31, all 64 cols.
  const int lane = tid & 63, wv = tid >> 6;
  const int wr = wv * 32;
  const int fr = lane & 15, kg = (lane >> 4) * 8;
  f32x4 acc[2][4] = {};
  #pragma unroll
  for (int ks = 0; ks < 2; ++ks) {
    const int k0 = ks*32 + kg;
    bf16x8 af[2], bfr[4];
    #pragma unroll
    for (int i = 0; i < 2; ++i) af[i] = *(const bf16x8*)&r1s[wr + i*16 + fr][k0];
    #pragma unroll
    for (int j = 0; j < 4; ++j) bfr[j] = *(const bf16x8*)&B2s[j*16 + fr][k0];
    #pragma unroll
    for (int i = 0; i < 2; ++i)
      #pragma unroll
      for (int j = 0; j < 4; ++j)
        acc[i][j] = __builtin_amdgcn_mfma_f32_16x16x32_bf16(af[i], bfr[j], acc[i][j], 0, 0, 0);
  }
  __syncthreads();   // all r1s reads done before overwrite
  const int dcol = lane & 15, drow4 = (lane >> 4) * 4;
  #pragma unroll
  for (int i = 0; i < 2; ++i)
    #pragma unroll
    for (int j = 0; j < 4; ++j)
      #pragma unroll
      for (int r = 0; r < 4; ++r) {
        int row = wr + i*16 + drow4 + r;
        int col = j*16 + dcol;
        r1s[row][col] = f2b(silu_f(acc[i][j][r]));
      }
  __syncthreads();
  for (int idx = tid * 8; idx < 128*64; idx += 256*8) {
    int r = idx >> 6, k = idx & 63;
    *(int4*)&r2[(ebase + r)*64 + k] = *(const int4*)&r1s[r][k];
  }
}

// WT[d][c] = W[c][d], bf16.  (128x128)
__global__ __launch_bounds__(256) void transpose_w_kernel(const float* __restrict__ W, ushort_t* __restrict__ WT) {
  int i = blockIdx.x * 256 + threadIdx.x;   // d*128 + c
  int d = i >> 7, c = i & 127;
  WT[i] = f2b(W[c*128 + d]);
}

// R3T[t][j] = R_w3[j][t], bf16.  t = c*4+l in [0,512), j in [0,64)
__global__ __launch_bounds__(256) void transpose_r3_kernel(const float* __restrict__ R3, ushort_t* __restrict__ R3T) {
  int i = blockIdx.x * 256 + threadIdx.x;   // t*64 + j
  int t = i >> 6, j = i & 63;
  R3T[i] = f2b(R3[j*512 + t]);
}

// MFMA GEMM (K=128): O[row, col] = sum_k A[row,k] * BT[col,k].
template<bool SCALED, bool EPI, bool L0>
__global__ __launch_bounds__(256) void mgemm_kernel(
    const ushort_t* __restrict__ A, size_t aStride,
    const ushort_t* __restrict__ BT,
    ushort_t* __restrict__ O, size_t oStride,
    const float* __restrict__ scaleBuf,
    const ushort_t* __restrict__ Hbuf,
    const float* __restrict__ wscL,
    const int* __restrict__ elem)
{
  __shared__ ushort_t As[128][136];
  __shared__ ushort_t Bs[128][136];
  const int tid = threadIdx.x;
  const size_t rowbase = (size_t)blockIdx.x * 128;

  for (int idx = tid * 8; idx < 128 * 128; idx += 256 * 8) {
    int r = idx >> 7, k = idx & 127;
    *(int4*)&Bs[r][k] = *(const int4*)&BT[(size_t)r * 128 + k];
  }
  for (int idx = tid * 8; idx < 128 * 128; idx += 256 * 8) {
    int r = idx >> 7, k = idx & 127;
    size_t grow = rowbase + r;
    const ushort_t* ap = A + grow * aStride + k;
    if (SCALED) {
      const float* sp = scaleBuf + (grow >> 4) * 128 + k;
      uint_t u[4];
      #pragma unroll
      for (int q = 0; q < 4; ++q) {
        ushort_t lo = f2b(b2f(ap[2*q])   * sp[2*q]);
        ushort_t hi = f2b(b2f(ap[2*q+1]) * sp[2*q+1]);
        u[q] = (uint_t)lo | ((uint_t)hi << 16);
      }
      *(int4*)&As[r][k] = make_int4((int)u[0], (int)u[1], (int)u[2], (int)u[3]);
    } else {
      *(int4*)&As[r][k] = *(const int4*)ap;
    }
  }
  __syncthreads();

  const int lane = tid & 63, wv = tid >> 6;
  const int wr = (wv >> 1) * 64, wc = (wv & 1) * 64;
  const int fr = lane & 15;
  const int kg = (lane >> 4) * 8;
  f32x4 acc[4][4] = {};
  #pragma unroll
  for (int ks = 0; ks < 4; ++ks) {
    const int k0 = ks * 32 + kg;
    bf16x8 af[4], bfr[4];
    #pragma unroll
    for (int i = 0; i < 4; ++i) af[i]  = *(const bf16x8*)&As[wr + i*16 + fr][k0];
    #pragma unroll
    for (int j = 0; j < 4; ++j) bfr[j] = *(const bf16x8*)&Bs[wc + j*16 + fr][k0];
    #pragma unroll
    for (int i = 0; i < 4; ++i)
      #pragma unroll
      for (int j = 0; j < 4; ++j)
        acc[i][j] = __builtin_amdgcn_mfma_f32_16x16x32_bf16(af[i], bfr[j], acc[i][j], 0, 0, 0);
  }

  const int dcol = lane & 15, drow4 = (lane >> 4) * 4;
  #pragma unroll
  for (int i = 0; i < 4; ++i) {
    #pragma unroll
    for (int j = 0; j < 4; ++j) {
      int col = wc + j*16 + dcol;
      #pragma unroll
      for (int r = 0; r < 4; ++r) {
        int row = wr + i*16 + drow4 + r;
        size_t grow = rowbase + row;
        float v = acc[i][j][r];
        if (EPI) {
          if (!L0 || ((grow & 15) == 0)) {
            int ee = elem[grow >> 4];
            v += b2f(Hbuf[grow * 128 + col]) * wscL[(size_t)ee * 128 + col];
          }
        }
        O[grow * oStride + col] = f2b(v);
      }
    }
  }
}

// w-GEMM, CSR-ordered: wb[local_row][t] = sum_k r2[eids[halfStart+local_row]][k] * R3T[t][k]
__global__ __launch_bounds__(256) void wgemm_kernel(
    const ushort_t* __restrict__ r2, const int* __restrict__ eids,
    const int* __restrict__ offs, int nb0,
    const ushort_t* __restrict__ R3T, ushort_t* __restrict__ wb)
{
  __shared__ ushort_t As[128][72];
  __shared__ ushort_t Bs[128][72];
  const int tid = threadIdx.x;
  const int rowbase = blockIdx.x * 128;
  const int colbase = blockIdx.y * 128;
  const int halfStart = offs[nb0];
  const int halfEnd   = offs[nb0 + kHalfN];

  for (int idx = tid * 8; idx < 128 * 64; idx += 256 * 8) {
    int r = idx >> 6, k = idx & 63;
    *(int4*)&Bs[r][k] = *(const int4*)&R3T[(size_t)(colbase + r) * 64 + k];
  }
  for (int idx = tid * 8; idx < 128 * 64; idx += 256 * 8) {
    int r = idx >> 6, k = idx & 63;
    int ii = halfStart + rowbase + r;
    int iic = ii < halfEnd ? ii : (halfEnd - 1);
    if (iic < 0) iic = 0;
    int e = eids[iic];
    *(int4*)&As[r][k] = *(const int4*)&r2[(size_t)e * 64 + k];
  }
  __syncthreads();

  const int lane = tid & 63, wv = tid >> 6;
  const int wr = (wv >> 1) * 64, wc = (wv & 1) * 64;
  const int fr = lane & 15;
  const int kg = (lane >> 4) * 8;
  f32x4 acc[4][4] = {};
  #pragma unroll
  for (int ks = 0; ks < 2; ++ks) {
    const int k0 = ks * 32 + kg;
    bf16x8 af[4], bfr[4];
    #pragma unroll
    for (int i = 0; i < 4; ++i) af[i]  = *(const bf16x8*)&As[wr + i*16 + fr][k0];
    #pragma unroll
    for (int j = 0; j < 4; ++j) bfr[j] = *(const bf16x8*)&Bs[wc + j*16 + fr][k0];
    #pragma unroll
    for (int i = 0; i < 4; ++i)
      #pragma unroll
      for (int j = 0; j < 4; ++j)
        acc[i][j] = __builtin_amdgcn_mfma_f32_16x16x32_bf16(af[i], bfr[j], acc[i][j], 0, 0, 0);
  }

  const int dcol = lane & 15, drow4 = (lane >> 4) * 4;
  #pragma unroll
  for (int i = 0; i < 4; ++i) {
    #pragma unroll
    for (int j = 0; j < 4; ++j) {
      int col = colbase + wc + j*16 + dcol;
      #pragma unroll
      for (int r = 0; r < 4; ++r) {
        int row = rowbase + wr + i*16 + drow4 + r;
        wb[(size_t)row * 512 + col] = f2b(acc[i][j][r]);
      }
    }
  }
}

// One block per node (n = nb0 + blockIdx.x). wb is CSR-local for this half.
constexpr int CH = 16;
__global__ __launch_bounds__(512) void gather_kernel(
    const int* __restrict__ offs, const int* __restrict__ eids,
    const int* __restrict__ ei, int nb0,
    const ushort_t* __restrict__ wb,
    const float* __restrict__ sh,
    const ushort_t* __restrict__ H,
    ushort_t* __restrict__ AGG)
{
  __shared__ ushort_t ws[CH][512];
  __shared__ ushort_t h0s[CH][128];
  __shared__ float shs[CH][16];
  int n = nb0 + blockIdx.x;
  int t = threadIdx.x;
  int l = t >> 7;       // wave-uniform
  int c = t & 127;
  const int wstart = offs[nb0];
  float a0=0,a1=0,a2=0,a3=0,a4=0,a5=0,a6=0;
  const int e0 = offs[n], e1 = offs[n+1];
  for (int base = e0; base < e1; base += CH) {
    const int cnt = min(CH, e1 - base);
    #pragma unroll
    for (int rep = 0; rep < 2; ++rep) {
      int idx = rep * 512 + t;
      int j = idx >> 6, seg = idx & 63;
      if (j < cnt)
        *(int4*)&ws[j][seg * 8] = *(const int4*)&wb[(size_t)(base - wstart + j) * 512 + seg * 8];
    }
    if (t < 256) {
      int j = t >> 4, seg = t & 15;
      if (j < cnt) {
        int e = eids[base + j];
        *(int4*)&h0s[j][seg * 8] = *(const int4*)&H[(size_t)ei[e] * 2048 + seg * 8];
      }
    } else if (t < 320) {
      int tt = t - 256, j = tt >> 2, seg = tt & 3;
      if (j < cnt)
        *(float4*)&shs[j][seg * 4] = *(const float4*)&sh[(size_t)eids[base + j] * 16 + seg * 4];
    }
    __syncthreads();
    for (int j = 0; j < cnt; ++j) {
      float wv = b2f(ws[j][(c << 2) | l]);
      float wh = wv * b2f(h0s[j][c]);
      if (l == 0) {
        a0 = fmaf(wh, shs[j][0], a0);
      } else if (l == 1) {
        float4 s4 = *(const float4*)&shs[j][0];
        a0 = fmaf(wh, s4.y, a0); a1 = fmaf(wh, s4.z, a1); a2 = fmaf(wh, s4.w, a2);
      } else if (l == 2) {
        float4 s4 = *(const float4*)&shs[j][4];
        float s8 = shs[j][8];
        a0 = fmaf(wh, s4.x, a0); a1 = fmaf(wh, s4.y, a1); a2 = fmaf(wh, s4.z, a2);
        a3 = fmaf(wh, s4.w, a3); a4 = fmaf(wh, s8, a4);
      } else {
        float4 sA = *(const float4*)&shs[j][8];
        float4 sB = *(const float4*)&shs[j][12];
        a0 = fmaf(wh, sA.y, a0); a1 = fmaf(wh, sA.z, a1); a2 = fmaf(wh, sA.w, a2);
        a3 = fmaf(wh, sB.x, a3); a4 = fmaf(wh, sB.y, a4); a5 = fmaf(wh, sB.z, a5);
        a6 = fmaf(wh, sB.w, a6);
      }
    }
    __syncthreads();
  }
  const float inv16 = 0.0625f;
  size_t baseo = (size_t)n * 2048 + c;
  if (l == 0) {
    AGG[baseo] = f2b(a0 * inv16);
  } else if (l == 1) {
    AGG[baseo + 1*128] = f2b(a0*inv16); AGG[baseo + 2*128] = f2b(a1*inv16); AGG[baseo + 3*128] = f2b(a2*inv16);
  } else if (l == 2) {
    AGG[baseo + 4*128] = f2b(a0*inv16); AGG[baseo + 5*128] = f2b(a1*inv16); AGG[baseo + 6*128] = f2b(a2*inv16);
    AGG[baseo + 7*128] = f2b(a3*inv16); AGG[baseo + 8*128] = f2b(a4*inv16);
  } else {
    AGG[baseo + 9*128]  = f2b(a0*inv16); AGG[baseo + 10*128] = f2b(a1*inv16); AGG[baseo + 11*128] = f2b(a2*inv16);
    AGG[baseo + 12*128] = f2b(a3*inv16); AGG[baseo + 13*128] = f2b(a4*inv16); AGG[baseo + 14*128] = f2b(a5*inv16);
    AGG[baseo + 15*128] = f2b(a6*inv16);
  }
}

__global__ __launch_bounds__(256) void scale_kernel(const ushort_t* __restrict__ M,
                                                    const int* __restrict__ elem,
                                                    const float* __restrict__ wprodL,
                                                    float* __restrict__ scale) {
  int i = blockIdx.x * 256 + threadIdx.x;  // n*128 + c
  int n = i >> 7, c = i & 127;
  float s = b2f(M[(size_t)n * 2048 + c]);
  const float* co = wprodL + ((size_t)elem[n] * 128 + c) * 3;
  scale[i] = co[0] + s * (co[1] + s * co[2]);
}

__global__ __launch_bounds__(64) void readout_kernel(const ushort_t* __restrict__ F,
                                                     const float* __restrict__ ro0,
                                                     const float* __restrict__ ro1,
                                                     const float* __restrict__ ro2,
                                                     float* __restrict__ out, int layer) {
  int n = blockIdx.x; int t = threadIdx.x;
  const ushort_t* fr = F + (size_t)n * 2048;   // feats[n][0][:]
  float f0 = b2f(fr[t]), f1 = b2f(fr[t + 64]);
  if (layer == 0) {
    float v = f0 * ro0[t] + f1 * ro0[t + 64];
    #pragma unroll
    for (int m = 32; m > 0; m >>= 1) v += __shfl_xor(v, m, 64);
    if (t == 0) out[n] = v;
  } else {
    float acc = 0.f;
    for (int h = 0; h < 16; ++h) {
      float p = f0 * ro1[t*16 + h] + f1 * ro1[(t + 64)*16 + h];
      #pragma unroll
      for (int m = 32; m > 0; m >>= 1) p += __shfl_xor(p, m, 64);
      acc = fmaf(silu_f(p), ro2[h], acc);
    }
    if (t == 0) out[n] += acc;
  }
}

extern "C" void kernel_launch(void* const* d_in, const int* in_sizes, int n_in,
                              void* d_out, int out_size, void* d_ws, size_t ws_size,
                              hipStream_t stream) {
  (void)in_sizes; (void)n_in; (void)out_size;
  const float* positions = (const float*)d_in[0];
  const float* node_attrs= (const float*)d_in[1];
  const float* shifts    = (const float*)d_in[2];
  const float* W_embed   = (const float*)d_in[3];
  const float* W_up      = (const float*)d_in[4];
  const float* R_w1      = (const float*)d_in[5];
  const float* R_w2      = (const float*)d_in[6];
  const float* R_w3      = (const float*)d_in[7];
  const float* W_out     = (const float*)d_in[8];
  const float* w_sc      = (const float*)d_in[9];
  const float* w_prod    = (const float*)d_in[10];
  const float* W_plin    = (const float*)d_in[11];
  const float* w_ro0     = (const float*)d_in[12];
  const float* ro_w1     = (const float*)d_in[13];
  const float* ro_w2     = (const float*)d_in[14];
  const int*   ei        = (const int*)d_in[15];
  float* out = (float*)d_out;

  char* ws_ptr = (char*)d_ws;
  size_t off = 0;
  auto alloc = [&](size_t nbytes) -> void* {
    void* p = ws_ptr + off;
    off += (nbytes + 255) & ~(size_t)255;
    return p;
  };
  const size_t PB = (size_t)kN * 16 * 128 * sizeof(ushort_t);  // 33.5 MB
  ushort_t* P0   = (ushort_t*)alloc(PB);
  ushort_t* P1   = (ushort_t*)alloc(PB);
  ushort_t* P2   = (ushort_t*)alloc(PB);
  float* shb     = (float*)alloc((size_t)kE * 16 * 4);          // 8.4 MB
  float* rbb     = (float*)alloc((size_t)kE * 8 * 4);           // 4.2 MB
  ushort_t* r2b  = (ushort_t*)alloc((size_t)kE * 64 * 2);       // 16.8 MB
  float* scaleb  = (float*)alloc((size_t)kN * 128 * 4);         // 4.2 MB
  ushort_t* wb   = (ushort_t*)alloc((size_t)kWbRows * 512 * 2); // 71.3 MB
  ushort_t* R3T0 = (ushort_t*)alloc(512 * 64 * 2);
  ushort_t* R3T1 = (ushort_t*)alloc(512 * 64 * 2);
  ushort_t* WTu0 = (ushort_t*)alloc(128 * 128 * 2);
  ushort_t* WTu1 = (ushort_t*)alloc(128 * 128 * 2);
  ushort_t* WTo0 = (ushort_t*)alloc(128 * 128 * 2);
  ushort_t* WTo1 = (ushort_t*)alloc(128 * 128 * 2);
  ushort_t* WTp0 = (ushort_t*)alloc(128 * 128 * 2);
  ushort_t* WTp1 = (ushort_t*)alloc(128 * 128 * 2);
  int* elemb  = (int*)alloc(kN * 4);
  int* counts = (int*)alloc(kN * 4);
  int* cursor = (int*)alloc(kN * 4);
  int* offsb  = (int*)alloc((kN + 1) * 4);
  int* eidsb  = (int*)alloc((size_t)kE * 4);
  if (off > ws_size) return;

  // ---- prep ----
  zero_ints_kernel<<<kN/256, 256, 0, stream>>>(counts, cursor);
  elem_kernel<<<kN/256, 256, 0, stream>>>(node_attrs, elemb);
  init_feats_kernel<<<(kN*128)/256, 256, 0, stream>>>(W_embed, elemb, P0);
  geom_kernel<<<kE/256, 256, 0, stream>>>(positions, shifts, ei, shb, rbb);
  count_kernel<<<kE/256, 256, 0, stream>>>(ei, counts);
  scan_kernel<<<1, 1024, 0, stream>>>(counts, offsb);
  fill_kernel<<<kE/256, 256, 0, stream>>>(ei, offsb, cursor, eidsb);
  transpose_w_kernel<<<64, 256, 0, stream>>>(W_up, WTu0);
  transpose_w_kernel<<<64, 256, 0, stream>>>(W_up + 16384, WTu1);
  transpose_w_kernel<<<64, 256, 0, stream>>>(W_out, WTo0);
  transpose_w_kernel<<<64, 256, 0, stream>>>(W_out + 16384, WTo1);
  transpose_w_kernel<<<64, 256, 0, stream>>>(W_plin, WTp0);
  transpose_w_kernel<<<64, 256, 0, stream>>>(W_plin + 16384, WTp1);
  transpose_r3_kernel<<<128, 256, 0, stream>>>(R_w3, R3T0);
  transpose_r3_kernel<<<128, 256, 0, stream>>>(R_w3 + 32768, R3T1);

  // ---- layer 0 (feats nonzero only at m=0) ----
  radial_kernel<<<kE/128, 256, 0, stream>>>(rbb, R_w1, R_w2, r2b);
  mgemm_kernel<false,false,false><<<kN/128, 256, 0, stream>>>(
      P0, 2048, WTu0, P1, 2048, nullptr, nullptr, nullptr, nullptr);
  wgemm_kernel<<<dim3(kWbTiles,4), 256, 0, stream>>>(r2b, eidsb, offsb, 0, R3T0, wb);
  gather_kernel<<<kHalfN, 512, 0, stream>>>(offsb, eidsb, ei, 0, wb, shb, P1, P2);
  wgemm_kernel<<<dim3(kWbTiles,4), 256, 0, stream>>>(r2b, eidsb, offsb, kHalfN, R3T0, wb);
  gather_kernel<<<kHalfN, 512, 0, stream>>>(offsb, eidsb, ei, kHalfN, wb, shb, P1, P2);
  mgemm_kernel<false,false,false><<<(kN*16)/128, 256, 0, stream>>>(
      P2, 128, WTo0, P0, 128, nullptr, nullptr, nullptr, nullptr);
  scale_kernel<<<(kN*128)/256, 256, 0, stream>>>(P0, elemb, w_prod, scaleb);
  mgemm_kernel<true,true,true><<<(kN*16)/128, 256, 0, stream>>>(
      P0, 128, WTp0, P2, 128, scaleb, P1, w_sc, elemb);
  readout_kernel<<<kN, 64, 0, stream>>>(P2, w_ro0, ro_w1, ro_w2, out, 0);

  // ---- layer 1 ----
  radial_kernel<<<kE/128, 256, 0, stream>>>(rbb, R_w1 + 512, R_w2 + 4096, r2b);
  mgemm_kernel<false,false,false><<<(kN*16)/128, 256, 0, stream>>>(
      P2, 128, WTu1, P1, 128, nullptr, nullptr, nullptr, nullptr);
  wgemm_kernel<<<dim3(kWbTiles,4), 256, 0, stream>>>(r2b, eidsb, offsb, 0, R3T1, wb);
  gather_kernel<<<kHalfN, 512, 0, stream>>>(offsb, eidsb, ei, 0, wb, shb, P1, P0);
  wgemm_kernel<<<dim3(kWbTiles,4), 256, 0, stream>>>(r2b, eidsb, offsb, kHalfN, R3T1, wb);
  gather_kernel<<<kHalfN, 512, 0, stream>>>(offsb, eidsb, ei, kHalfN, wb, shb, P1, P0);
  mgemm_kernel<false,false,false><<<(kN*16)/128, 256, 0, stream>>>(
      P0, 128, WTo1, P2, 128, nullptr, nullptr, nullptr, nullptr);
  scale_kernel<<<(kN*128)/256, 256, 0, stream>>>(P2, elemb, w_prod + 3840, scaleb);
  mgemm_kernel<true,true,false><<<(kN*16)/128, 256, 0, stream>>>(
      P2, 128, WTp1, P0, 128, scaleb, P1, w_sc + 1280, elemb);
  readout_kernel<<<kN, 64, 0, stream>>>(P0, w_ro0, ro_w1, ro_w2, out, 1);
}